// Round 10
// baseline (610.506 us; speedup 1.0000x reference)
//
#include <hip/hip_runtime.h>
#include <cstdint>
#include <math.h>

#define NP 9216     // 96*96
#define NP2 2304    // 48*48
#define KH 12       // harmonics k=0..12
#define NMOM 78     // 13 * 6
#define GRID 512

__device__ __forceinline__ float gelu_ex(float v){
  return 0.5f*v*(1.0f+erff(v*0.70710678118654752440f));
}
__device__ __forceinline__ float sigm(float v){
  return 1.0f/(1.0f+__expf(-v));
}

// One-shot grid barrier, slot used exactly once per kernel invocation.
// Slots zeroed by captured hipMemsetAsync before each launch.
__device__ __forceinline__ void gsync(unsigned* bar, int slot, unsigned nb){
  __threadfence();                       // release: flush this block's writes
  __syncthreads();
  if (threadIdx.x==0){
    unsigned* cnt  = bar + slot*64;
    unsigned* flag = bar + slot*64 + 16;
    unsigned v = __hip_atomic_fetch_add(cnt, 1u, __ATOMIC_ACQ_REL, __HIP_MEMORY_SCOPE_AGENT);
    if (v == nb-1u){
      __hip_atomic_store(flag, 1u, __ATOMIC_RELEASE, __HIP_MEMORY_SCOPE_AGENT);
    } else {
      while (!__hip_atomic_load(flag, __ATOMIC_ACQUIRE, __HIP_MEMORY_SCOPE_AGENT))
        __builtin_amdgcn_s_sleep(1);
    }
  }
  __syncthreads();
}

struct MParams {
  const float *x;
  const float *cab_w1,*cab_w2,*cab_aw1,*cab_aw2,*sq1_w,*sq2_w,*ca_qkv_w,*ca_fus_w;
  const float *sa_qkv_w,*sa_fus_w,*un1_w,*un2_w,*da_w1,*da_dw_w,*da_pw;
  const float *cab_b1,*cab_b2,*cab_ab1,*cab_ab2,*sq1_b,*sq2_b,*ca_qkv_b,*ca_fus_b;
  const float *sa_qkv_b,*sa_fus_b,*un1_b,*un2_b,*da_b1,*da_dw_b,*da_pb;
  const float *ln1_w,*ln1_b,*ln2_w,*ln2_b,*ca_t,*sa_t;
  float *xn,*z1,*c1b,*cb,*u,*psb,*xsm,*ypart,*spart,*mompart;
  float2 *qarr;
  float *d1,*dg,*out;
  unsigned *bar;
};

__global__ __launch_bounds__(256,2) void mega(MParams P)
{
  __shared__ float smem[2112];   // 8448 B union across phases
  const int G = gridDim.x;
  const int tid = threadIdx.x;

  // ---------------- Phase A: channel-LN + sq1 1x1 (32->8). 576 units ----------------
  {
    float (*sred)[8][32] = (float(*)[8][32])smem;        // [2][8][32]
    float (*xnsh)[33]    = (float(*)[33])(smem+512);     // [32][33]
    for (int u_=blockIdx.x; u_<576; u_+=G){
      int p = tid & 31, sl = tid >> 5;
      int pix = u_*32 + p;
      int b = pix / NP, n = pix % NP;
      const float* xp = P.x + (size_t)b*32*NP + (size_t)(sl*4)*NP + n;
      float v[4]; float s=0.f, s2=0.f;
#pragma unroll
      for (int c=0;c<4;c++){ float t=xp[(size_t)c*NP]; v[c]=t; s+=t; s2+=t*t; }
      sred[0][sl][p]=s; sred[1][sl][p]=s2;
      __syncthreads();
      s=0.f; s2=0.f;
#pragma unroll
      for (int g=0;g<8;g++){ s += sred[0][g][p]; s2 += sred[1][g][p]; }
      float mu = s*(1.f/32.f);
      float var = s2*(1.f/32.f)-mu*mu;
      float rs = rsqrtf(var+1e-5f);
      float* xo = P.xn + (size_t)b*32*NP + (size_t)(sl*4)*NP + n;
#pragma unroll
      for (int c=0;c<4;c++){
        int cc = sl*4+c;
        float t = (v[c]-mu)*rs*P.ln1_w[cc]+P.ln1_b[cc];
        xo[(size_t)c*NP] = t;
        xnsh[p][cc] = t;
      }
      __syncthreads();
      float vv[32];
#pragma unroll
      for (int c=0;c<32;c++) vv[c]=xnsh[p][c];
      float a = P.sq1_b[sl];
#pragma unroll
      for (int c=0;c<32;c++) a += vv[c]*P.sq1_w[sl*32+c];
      P.z1[(size_t)b*8*NP + (size_t)sl*NP + n] = a;
      __syncthreads();
    }
  }
  gsync(P.bar, 0, GRID);

  // ---------------- Phase B: cab1 (576) || sq2 (144). 720 units ----------------
  {
    float (*red5)[5] = (float(*)[5])smem;                // [4][5]
    for (int u_=blockIdx.x; u_<720; u_+=G){
      if (u_ < 576){
        int og = u_/72, pb = u_%72;
        int idx = pb*256+tid;
        int b = idx/NP, n = idx%NP, i = n/96, j = n%96;
        const float* xb = P.xn + (size_t)b*32*NP;
        const float* wb = P.cab_w1 + og*288;
        int o_[9]; float m_[9]; int d=0;
#pragma unroll
        for (int di=0;di<3;di++){
          int ii=i+di-1; bool vi = (unsigned)ii<96u;
#pragma unroll
          for (int dj=0;dj<3;dj++){
            int jj=j+dj-1; bool vld = vi && ((unsigned)jj<96u);
            o_[d] = vld ? ii*96+jj : 0; m_[d] = vld ? 1.f : 0.f; d++;
          }
        }
        float accd[9] = {0,0,0,0,0,0,0,0,0};
        for (int c=0;c<32;c++){
          const float* xp = xb + (size_t)c*NP;
          const float* wp = wb + c*9;
          float t[9];
#pragma unroll
          for (int d2=0;d2<9;d2++) t[d2] = xp[o_[d2]];
#pragma unroll
          for (int d2=0;d2<9;d2++) accd[d2] += t[d2]*wp[d2];
        }
        float acc = P.cab_b1[og];
#pragma unroll
        for (int d2=0;d2<9;d2++) acc += accd[d2]*m_[d2];
        P.c1b[(size_t)b*8*NP + (size_t)og*NP + n] = gelu_ex(acc);
      } else {
        int u2 = u_-576;
        int pr = u2/18, pb = u2%18;
        int idx = pb*256+tid;
        int b = idx/NP2, n = idx%NP2, i = n/48, j = n%48;
        int ocA = pr, ocB = pr+8;
        int gA = ocA>>1, gB = ocB>>1;
        const float* zpA = P.z1 + ((size_t)b*8+gA)*NP + (size_t)(2*i)*96 + 2*j;
        const float* zpB = P.z1 + ((size_t)b*8+gB)*NP + (size_t)(2*i)*96 + 2*j;
        const float* w = P.sq2_w;
        float vA = zpA[0]*w[ocA*4]+zpA[1]*w[ocA*4+1]+zpA[96]*w[ocA*4+2]+zpA[97]*w[ocA*4+3]+P.sq2_b[ocA];
        float vB = zpB[0]*w[ocB*4]+zpB[1]*w[ocB*4+1]+zpB[96]*w[ocB*4+2]+zpB[97]*w[ocB*4+3]+P.sq2_b[ocB];
        P.u[((size_t)b*16+2*pr)*NP2 + n]   = vA;
        P.u[((size_t)b*16+2*pr+1)*NP2 + n] = vB;
        int wv=tid>>6, ln=tid&63;
        float st[5]={vA,vB,vA*vA,vB*vB,vA*vB};
#pragma unroll
        for (int k=0;k<5;k++){
          float r=st[k];
#pragma unroll
          for (int m=1;m<64;m<<=1) r+=__shfl_xor(r,m,64);
          if (ln==0) red5[wv][k]=r;
        }
        __syncthreads();
        if (tid<5){
          float r = red5[0][tid]+red5[1][tid]+red5[2][tid]+red5[3][tid];
          P.spart[(b*9 + (pb%9))*40 + pr*5 + tid] = r;
        }
        __syncthreads();
      }
    }
  }
  gsync(P.bar, 1, GRID);

  // ---------------- Phase C: cab2 (576) || qkmom (288). 864 units ----------------
  {
    for (int u_=blockIdx.x; u_<864; u_+=G){
      if (u_ < 576){
        float (*red4)[4] = (float(*)[4])smem;            // [4][4]
        int og = u_/72, pb = u_%72;
        int idx = pb*256+tid;
        int b = idx/NP, n = idx%NP, i = n/96, j = n%96;
        int o_[9]; float m_[9]; int d=0;
#pragma unroll
        for (int di=0;di<3;di++){
          int ii=i+di-1; bool vi = (unsigned)ii<96u;
#pragma unroll
          for (int dj=0;dj<3;dj++){
            int jj=j+dj-1; bool vld = vi && ((unsigned)jj<96u);
            o_[d] = vld ? ii*96+jj : 0; m_[d] = vld ? 1.f : 0.f; d++;
          }
        }
        float acc[4];
#pragma unroll
        for (int k=0;k<4;k++) acc[k]=P.cab_b2[og*4+k];
        const float* cbp = P.c1b + (size_t)b*8*NP;
        for (int c=0;c<8;c++){
          const float* xp = cbp + (size_t)c*NP;
          float t[9];
#pragma unroll
          for (int d2=0;d2<9;d2++) t[d2] = xp[o_[d2]]*m_[d2];
#pragma unroll
          for (int k=0;k<4;k++){
            const float* wp = P.cab_w2 + (og*4+k)*72 + c*9;
#pragma unroll
            for (int d2=0;d2<9;d2++) acc[k] += t[d2]*wp[d2];
          }
        }
        int wv = tid>>6, ln = tid&63;
#pragma unroll
        for (int k=0;k<4;k++){
          P.cb[(size_t)b*32*NP + (size_t)(og*4+k)*NP + n] = acc[k];
          float r = acc[k];
#pragma unroll
          for (int m=1;m<64;m<<=1) r += __shfl_xor(r, m, 64);
          if (ln==0) red4[wv][k]=r;
        }
        __syncthreads();
        if (tid<4){
          float r = red4[0][tid]+red4[1][tid]+red4[2][tid]+red4[3][tid];
          P.ypart[(og*72+pb)*4 + tid] = r;
        }
        __syncthreads();
      } else {
        float (*red16)[80] = (float(*)[80])smem;         // [16][80]
        int u2 = u_-576;
        int bh = u2/9, ch = u2%9;
        int n = ch*256 + tid;
        int b = bh>>4, h = bh&15;
        int p = h&7, s = h>>3;
        int cc0=2*p, cc1=2*p+1;
        int oc0 = 2*(cc0&7)+(cc0>>3);
        int oc1 = 2*(cc1&7)+(cc1>>3);
        float AA[2], BB[2], CCc[2];
#pragma unroll
        for (int t2=0;t2<2;t2++){
          int oc = t2? oc1:oc0;
          int p2 = oc>>1, dd = oc&1;
          float st[5]={0,0,0,0,0};
          for (int ib=0; ib<9; ib++){
#pragma unroll
            for (int k=0;k<5;k++) st[k] += P.spart[(b*9+ib)*40 + p2*5 + k];
          }
          float S0=st[0],S1=st[1],Q00=st[2],Q11=st[3],Q01=st[4];
          float Sd = dd? S1:S0;
          float Qdd = dd? Q11:Q00;
          float cu0[2],cu1[2],ccst[2];
#pragma unroll
          for (int hh=0;hh<2;hh++){
            int h2=p2+8*hh;
            float th2=P.ca_t[h2];
            float aq=P.ca_qkv_w[(2*p2+dd)*6+hh], bq=P.ca_qkv_b[(2*p2+dd)*6+hh];
            float nq=fmaxf(sqrtf(fmaxf(aq*aq*Qdd+2.f*aq*bq*Sd+2304.f*bq*bq,0.f)),1e-12f);
            float m2[2],av[2],bv[2];
#pragma unroll
            for (int e=0;e<2;e++){
              float Se_=e?S1:S0, Qee=e?Q11:Q00, Qde=(dd==e)?Qdd:Q01;
              float ak=P.ca_qkv_w[(2*p2+e)*6+2+hh], bk=P.ca_qkv_b[(2*p2+e)*6+2+hh];
              float nk=fmaxf(sqrtf(fmaxf(ak*ak*Qee+2.f*ak*bk*Se_+2304.f*bk*bk,0.f)),1e-12f);
              float D=aq*ak*Qde + aq*bk*Sd + bq*ak*Se_ + 2304.f*bq*bk;
              m2[e]=th2*D/(nq*nk);
              av[e]=P.ca_qkv_w[(2*p2+e)*6+4+hh]; bv[e]=P.ca_qkv_b[(2*p2+e)*6+4+hh];
            }
            float mx=fmaxf(m2[0],m2[1]);
            float e0=__expf(m2[0]-mx), e1=__expf(m2[1]-mx);
            float inv=1.f/(e0+e1);
            cu0[hh]=e0*inv*av[0]; cu1[hh]=e1*inv*av[1]; ccst[hh]=e0*inv*bv[0]+e1*inv*bv[1];
          }
          float f0=P.ca_fus_w[oc*2], f1=P.ca_fus_w[oc*2+1];
          AA[t2]=f0*cu0[0]+f1*cu0[1];
          BB[t2]=f0*cu1[0]+f1*cu1[1];
          CCc[t2]=f0*ccst[0]+f1*ccst[1]+P.ca_fus_b[oc];
        }
        const float* u00 = P.u + ((size_t)b*16 + (oc0>>1)*2)*NP2;
        const float* u01 = u00 + NP2;
        const float* u10 = P.u + ((size_t)b*16 + (oc1>>1)*2)*NP2;
        const float* u11 = u10 + NP2;
        float w0 = AA[0]*u00[n]+BB[0]*u01[n]+CCc[0];
        float w1 = AA[1]*u10[n]+BB[1]*u11[n]+CCc[1];
        float k0 = P.sa_qkv_w[cc0*6+2+s]*w0+P.sa_qkv_b[cc0*6+2+s];
        float k1 = P.sa_qkv_w[cc1*6+2+s]*w1+P.sa_qkv_b[cc1*6+2+s];
        float rnk = 1.f/fmaxf(sqrtf(k0*k0+k1*k1),1e-12f);
        float kc = k0*rnk, ks = k1*rnk;
        float q0 = P.sa_qkv_w[cc0*6+s]*w0+P.sa_qkv_b[cc0*6+s];
        float q1 = P.sa_qkv_w[cc1*6+s]*w1+P.sa_qkv_b[cc1*6+s];
        float rnq = 1.f/fmaxf(sqrtf(q0*q0+q1*q1),1e-12f);
        P.qarr[bh*NP2+n] = make_float2(q0*rnq, q1*rnq);

        int grp = tid>>4, gl = tid&15;
        float c = 1.f, sn = 0.f;
#pragma unroll
        for (int k=0;k<=KH;k++){
          float vals[6] = {c, sn, c*w0, sn*w0, c*w1, sn*w1};
#pragma unroll
          for (int jv=0;jv<6;jv++){
            float r = vals[jv];
            r += __shfl_xor(r, 1, 64);
            r += __shfl_xor(r, 2, 64);
            r += __shfl_xor(r, 4, 64);
            r += __shfl_xor(r, 8, 64);
            if (gl==0) red16[grp][k*6+jv] = r;
          }
          float cn = c*kc - sn*ks;
          sn = sn*kc + c*ks;
          c = cn;
        }
        __syncthreads();
        if (tid < NMOM){
          float r = 0.f;
#pragma unroll
          for (int g=0;g<16;g++) r += red16[g][tid];
          P.mompart[(bh*9+ch)*NMOM + tid] = r;
        }
        __syncthreads();
      }
    }
  }
  gsync(P.bar, 2, GRID);

  // ---------------- Phase D: rows (144 units) ----------------
  {
    float (*msh)[80] = (float(*)[80])smem;               // [2][80]
    float (*fsh)[13] = (float(*)[13])(smem+160);         // [2][13]
    for (int u_=blockIdx.x; u_<144; u_+=G){
      int bp = u_/9, ch = u_%9;
      int b = bp>>3, p = bp&7;
      int n = ch*256 + tid;
      if (tid < 26){
        int hh = tid/13, k = tid%13;
        double t = (double)P.sa_t[p+8*hh];
        double fac;
        if (fabs(t) < 1e-3){
          double xh = 0.5*t;
          double pk = 1.0;
          for (int q=1;q<=k;q++) pk *= xh/(double)q;
          double Ik = pk*(1.0 + xh*xh/(double)(k+1));
          fac = (k? 2.0:1.0)*Ik;
        } else {
          const int KS = 36;
          double ip1 = 0.0, ik = 1e-280, sum2 = 0.0;
          double vk = 0.0, v0 = 0.0;
          for (int q=KS; q>=1; --q){
            if (q == k) vk = ik;
            sum2 += ik;
            double im1 = ip1 + (2.0*(double)q/t)*ik;
            ip1 = ik; ik = im1;
          }
          v0 = ik;
          if (k == 0) vk = v0;
          double total = v0 + 2.0*sum2;
          double scale = exp(t)/total;
          fac = (k? 2.0:1.0)*vk*scale;
        }
        fsh[hh][k] = (float)fac;
      }
      if (tid < 2*NMOM){
        int hh = tid/NMOM, jj = tid%NMOM;
        float ssum = 0.f;
        for (int ib=0; ib<9; ib++)
          ssum += P.mompart[((size_t)(b*16+p+8*hh)*9+ib)*NMOM + jj];
        msh[hh][jj] = ssum;
      }
      __syncthreads();
      if (tid < 2*NMOM){
        int hh = tid/NMOM, jj = tid%NMOM;
        msh[hh][jj] *= fsh[hh][jj/6];
      }
      __syncthreads();
      float o[2][2];
#pragma unroll
      for (int hh=0;hh<2;hh++){
        float2 q = P.qarr[(size_t)(b*16+p+8*hh)*NP2 + n];
        float c = 1.f, sn = 0.f;
        float Se=0.f, S0=0.f, S1=0.f;
#pragma unroll
        for (int k=0;k<=KH;k++){
          const float* mk = &msh[hh][k*6];
          Se += c*mk[0] + sn*mk[1];
          S0 += c*mk[2] + sn*mk[3];
          S1 += c*mk[4] + sn*mk[5];
          float cn = c*q.x - sn*q.y;
          sn = sn*q.x + c*q.y;
          c = cn;
        }
        float rSe = 1.f/Se;
        float av0=P.sa_qkv_w[(2*p)*6+4+hh],  bv0=P.sa_qkv_b[(2*p)*6+4+hh];
        float av1=P.sa_qkv_w[(2*p+1)*6+4+hh],bv1=P.sa_qkv_b[(2*p+1)*6+4+hh];
        o[hh][0]=av0*S0*rSe+bv0;
        o[hh][1]=av1*S1*rSe+bv1;
      }
      float zz0 = o[0][0]*P.sa_fus_w[(2*p)*2]   + o[1][0]*P.sa_fus_w[(2*p)*2+1]   + P.sa_fus_b[2*p];
      float zz1 = o[0][1]*P.sa_fus_w[(2*p+1)*2] + o[1][1]*P.sa_fus_w[(2*p+1)*2+1] + P.sa_fus_b[2*p+1];
      int i=n/48, j=n%48;
      float* pb2 = P.psb + ((size_t)b*8+p)*NP;
#pragma unroll
      for (int k=0;k<4;k++){
        int od = 4*p+k;
        float v = zz0*P.un1_w[od*2] + zz1*P.un1_w[od*2+1] + P.un1_b[od];
        pb2[(size_t)(2*i+(k>>1))*96 + 2*j + (k&1)] = v;
      }
      __syncthreads();
    }
  }
  gsync(P.bar, 3, GRID);

  // ---------------- Phase E: SE + un2 + residual + LN2 + da_w1 (576 units) ----------------
  {
    float (*sred)[8][32] = (float(*)[8][32])smem;        // [2][8][32]
    float (*xsh)[33]     = (float(*)[33])(smem+512);     // [32][33]
    float *y2sh          = smem+1568;                    // [32]
    for (int u_=blockIdx.x; u_<576; u_+=G){
      int p = tid & 31, sl = tid >> 5;
      int pix = u_*32 + p;
      int b = pix/NP, n = pix%NP;
      if (tid < 32){
        int c = tid;
        float ssum = 0.f;
        for (int ib=0; ib<36; ib++)
          ssum += P.ypart[((c>>2)*72 + b*36 + ib)*4 + (c&3)];
        float pr = ssum*(1.f/9216.f)*P.cab_aw1[c];
#pragma unroll
        for (int m=1;m<32;m<<=1) pr += __shfl_xor(pr, m, 64);
        float y1 = fmaxf(pr+P.cab_ab1[0], 0.f);
        y2sh[c] = sigm(P.cab_aw2[c]*y1+P.cab_ab2[c]);
      }
      float pg[8];
#pragma unroll
      for (int g=0;g<8;g++) pg[g]=P.psb[((size_t)b*8+g)*NP+n];
      __syncthreads();
      float xv[4]; float s=0.f,s2=0.f;
#pragma unroll
      for (int c=0;c<4;c++){
        int cc = sl*4+c;
        float a=P.un2_b[cc];
#pragma unroll
        for (int g=0;g<8;g++) a+=pg[g]*P.un2_w[cc*8+g];
        size_t off=((size_t)b*32+cc)*NP+n;
        float t = P.x[off]+a+P.cb[off]*y2sh[cc];
        xv[c]=t; P.xsm[off]=t; s+=t; s2+=t*t;
      }
      sred[0][sl][p]=s; sred[1][sl][p]=s2;
      __syncthreads();
      s=0.f; s2=0.f;
#pragma unroll
      for (int g=0;g<8;g++){ s += sred[0][g][p]; s2 += sred[1][g][p]; }
      float mu=s*(1.f/32.f), var=s2*(1.f/32.f)-mu*mu, rs=rsqrtf(var+1e-5f);
#pragma unroll
      for (int c=0;c<4;c++){
        int cc = sl*4+c;
        xsh[p][cc] = (xv[c]-mu)*rs*P.ln2_w[cc]+P.ln2_b[cc];
      }
      __syncthreads();
      float vv[32];
#pragma unroll
      for (int c=0;c<32;c++) vv[c]=xsh[p][c];
#pragma unroll
      for (int k=0;k<4;k++){
        int o = sl*4+k;
        float a=P.da_b1[o];
#pragma unroll
        for (int cc=0;cc<32;cc++) a+=vv[cc]*P.da_w1[o*32+cc];
        P.d1[((size_t)b*32+o)*NP+n]=a;
      }
      __syncthreads();
    }
  }
  gsync(P.bar, 4, GRID);

  // ---------------- Phase F: 7x7 depthwise gate (1152 units) ----------------
  {
    for (int u_=blockIdx.x; u_<1152; u_+=G){
      int idx = u_*256+tid;
      int pl = idx/4608, n2 = idx%4608;
      int i2 = n2/96, j = n2%96;
      int c = pl&31;
      const float* dp = P.d1 + (size_t)pl*NP;
      const float* w0p = P.da_dw_w + (2*c)*49;
      const float* w1p = P.da_dw_w + (2*c+1)*49;
      float a0=P.da_dw_b[2*c], a1=P.da_dw_b[2*c+1];
      float c0=P.da_dw_b[2*c], c1=P.da_dw_b[2*c+1];
#pragma unroll
      for (int di=0;di<8;di++){
        int ii=2*i2-3+di; if ((unsigned)ii>=96u) continue;
        const float* rowp = dp + ii*96;
        float t[7];
#pragma unroll
        for (int dj=0;dj<7;dj++){
          int jj=j+dj-3;
          t[dj] = ((unsigned)jj<96u) ? rowp[jj] : 0.f;
        }
        if (di<7){
#pragma unroll
          for (int dj=0;dj<7;dj++){ a0 += t[dj]*w0p[di*7+dj]; a1 += t[dj]*w1p[di*7+dj]; }
        }
        if (di>0){
#pragma unroll
          for (int dj=0;dj<7;dj++){ c0 += t[dj]*w0p[(di-1)*7+dj]; c1 += t[dj]*w1p[(di-1)*7+dj]; }
        }
      }
      P.dg[(size_t)pl*NP + (size_t)(2*i2)*96 + j]   = gelu_ex(a0)*sigm(a1);
      P.dg[(size_t)pl*NP + (size_t)(2*i2+1)*96 + j] = gelu_ex(c0)*sigm(c1);
    }
  }
  gsync(P.bar, 5, GRID);

  // ---------------- Phase G: final 1x1 conv + residual -> out (288 units) ----------------
  {
    float (*xsh)[33] = (float(*)[33])smem;               // [64][33]
    for (int u_=blockIdx.x; u_<288; u_+=G){
      int p = tid & 63, sl = tid >> 6;
      int pix = u_*64 + p;
      int b = pix/NP, n = pix%NP;
      const float* dp = P.dg + ((size_t)b*32 + sl*8)*NP + n;
#pragma unroll
      for (int c=0;c<8;c++) xsh[p][sl*8+c]=dp[(size_t)c*NP];
      __syncthreads();
      float vv[32];
#pragma unroll
      for (int c=0;c<32;c++) vv[c]=xsh[p][c];
#pragma unroll
      for (int k=0;k<8;k++){
        int o = sl*8+k;
        float a=P.da_pb[o];
#pragma unroll
        for (int cc=0;cc<32;cc++) a+=vv[cc]*P.da_pw[o*32+cc];
        size_t off=((size_t)b*32+o)*NP+n;
        P.out[off]=P.xsm[off]+a;
      }
      __syncthreads();
    }
  }
}

extern "C" void kernel_launch(void* const* d_in, const int* in_sizes, int n_in,
                              void* d_out, int out_size, void* d_ws, size_t ws_size,
                              hipStream_t stream) {
  (void)in_sizes; (void)n_in; (void)out_size; (void)ws_size;
  float* ws=(float*)d_ws;
  MParams mp;
  mp.x        =(const float*)d_in[0];
  mp.cab_w1   =(const float*)d_in[1];
  mp.cab_w2   =(const float*)d_in[2];
  mp.cab_aw1  =(const float*)d_in[3];
  mp.cab_aw2  =(const float*)d_in[4];
  mp.sq1_w    =(const float*)d_in[5];
  mp.sq2_w    =(const float*)d_in[6];
  mp.ca_qkv_w =(const float*)d_in[7];
  mp.ca_fus_w =(const float*)d_in[8];
  mp.sa_qkv_w =(const float*)d_in[9];
  mp.sa_fus_w =(const float*)d_in[10];
  mp.un1_w    =(const float*)d_in[11];
  mp.un2_w    =(const float*)d_in[12];
  mp.da_w1    =(const float*)d_in[13];
  mp.da_dw_w  =(const float*)d_in[14];
  mp.da_pw    =(const float*)d_in[15];
  mp.cab_b1   =(const float*)d_in[16];
  mp.cab_b2   =(const float*)d_in[17];
  mp.cab_ab1  =(const float*)d_in[18];
  mp.cab_ab2  =(const float*)d_in[19];
  mp.sq1_b    =(const float*)d_in[20];
  mp.sq2_b    =(const float*)d_in[21];
  mp.ca_qkv_b =(const float*)d_in[22];
  mp.ca_fus_b =(const float*)d_in[23];
  mp.sa_qkv_b =(const float*)d_in[24];
  mp.sa_fus_b =(const float*)d_in[25];
  mp.un1_b    =(const float*)d_in[26];
  mp.un2_b    =(const float*)d_in[27];
  mp.da_b1    =(const float*)d_in[28];
  mp.da_dw_b  =(const float*)d_in[29];
  mp.da_pb    =(const float*)d_in[30];
  mp.ln1_w    =(const float*)d_in[31];
  mp.ln1_b    =(const float*)d_in[32];
  mp.ln2_w    =(const float*)d_in[33];
  mp.ln2_b    =(const float*)d_in[34];
  mp.ca_t     =(const float*)d_in[35];
  mp.sa_t     =(const float*)d_in[36];

  mp.xn     = ws;               // 589824 (reused as d1 after phase B)
  mp.z1     = ws + 589824;      // 147456
  mp.c1b    = ws + 737280;      // 147456
  mp.cb     = ws + 884736;      // 589824 (cbuf; reused as dg after phase E)
  mp.u      = ws + 1474560;     // 73728
  mp.psb    = ws + 1548288;     // 147456
  mp.xsm    = ws + 1695744;     // 589824
  mp.ypart  = ws + 2285568;     // 2304
  mp.spart  = ws + 2294784;     // 720 (+pad)
  mp.qarr   = (float2*)(ws + 2295552);  // 147456 floats
  mp.mompart= ws + 2443008;     // 22464
  mp.d1     = mp.xn;            // alias: xn dead after phase B
  mp.dg     = mp.cb;            // alias: cb dead after phase E
  mp.out    = (float*)d_out;
  mp.bar    = (unsigned*)(ws + 2465472);  // 6 slots x 64 u32 = 1536 B

  hipMemsetAsync((void*)mp.bar, 0, 6*64*sizeof(unsigned), stream);
  mega<<<GRID, 256, 0, stream>>>(mp);
}

// Round 11
// 351.160 us; speedup vs baseline: 1.7385x; 1.7385x over previous
//
#include <hip/hip_runtime.h>
#include <cstdint>
#include <math.h>

#define NP 9216     // 96*96
#define NP2 2304    // 48*48
#define KH 12       // harmonics k=0..12
#define NMOM 78     // 13 * 6
#define GRID 512

__device__ __forceinline__ float gelu_ex(float v){
  return 0.5f*v*(1.0f+erff(v*0.70710678118654752440f));
}
__device__ __forceinline__ float sigm(float v){
  return 1.0f/(1.0f+__expf(-v));
}

// One-shot grid barrier. RELAXED polling (agent-scope atomics execute at the
// coherence point, no per-poll cache invalidate); single threadfence on each
// side does the L2 writeback / invalidate ONCE. Slots zeroed by captured
// hipMemsetAsync before each launch.
__device__ __forceinline__ void gsync(unsigned* bar, int slot, unsigned nb){
  __syncthreads();                        // all block stores drained (vmcnt 0)
  if (threadIdx.x==0){
    __threadfence();                      // release: write back this XCD's L2
    unsigned* cnt = bar + slot*64;
    __hip_atomic_fetch_add(cnt, 1u, __ATOMIC_RELAXED, __HIP_MEMORY_SCOPE_AGENT);
    while (__hip_atomic_load(cnt, __ATOMIC_RELAXED, __HIP_MEMORY_SCOPE_AGENT) < nb)
      __builtin_amdgcn_s_sleep(4);
    __threadfence();                      // acquire: invalidate stale lines
  }
  __syncthreads();
}

struct MParams {
  const float *x;
  const float *cab_w1,*cab_w2,*cab_aw1,*cab_aw2,*sq1_w,*sq2_w,*ca_qkv_w,*ca_fus_w;
  const float *sa_qkv_w,*sa_fus_w,*un1_w,*un2_w,*da_w1,*da_dw_w,*da_pw;
  const float *cab_b1,*cab_b2,*cab_ab1,*cab_ab2,*sq1_b,*sq2_b,*ca_qkv_b,*ca_fus_b;
  const float *sa_qkv_b,*sa_fus_b,*un1_b,*un2_b,*da_b1,*da_dw_b,*da_pb;
  const float *ln1_w,*ln1_b,*ln2_w,*ln2_b,*ca_t,*sa_t;
  float *xn,*z1,*c1b,*cb,*u,*psb,*xsm,*ypart,*spart,*mompart;
  float2 *qarr;
  float *d1,*dg,*out;
  unsigned *bar;
};

__global__ __launch_bounds__(256,2) void mega(MParams P)
{
  __shared__ float smem[2112];   // 8448 B union across phases
  const int G = gridDim.x;
  const int tid = threadIdx.x;

  // ---------------- Phase A: channel-LN + sq1 1x1 (32->8). 576 units ----------------
  {
    float (*sred)[8][32] = (float(*)[8][32])smem;        // [2][8][32]
    float (*xnsh)[33]    = (float(*)[33])(smem+512);     // [32][33]
    for (int u_=blockIdx.x; u_<576; u_+=G){
      int p = tid & 31, sl = tid >> 5;
      int pix = u_*32 + p;
      int b = pix / NP, n = pix % NP;
      const float* xp = P.x + (size_t)b*32*NP + (size_t)(sl*4)*NP + n;
      float v[4]; float s=0.f, s2=0.f;
#pragma unroll
      for (int c=0;c<4;c++){ float t=xp[(size_t)c*NP]; v[c]=t; s+=t; s2+=t*t; }
      sred[0][sl][p]=s; sred[1][sl][p]=s2;
      __syncthreads();
      s=0.f; s2=0.f;
#pragma unroll
      for (int g=0;g<8;g++){ s += sred[0][g][p]; s2 += sred[1][g][p]; }
      float mu = s*(1.f/32.f);
      float var = s2*(1.f/32.f)-mu*mu;
      float rs = rsqrtf(var+1e-5f);
      float* xo = P.xn + (size_t)b*32*NP + (size_t)(sl*4)*NP + n;
#pragma unroll
      for (int c=0;c<4;c++){
        int cc = sl*4+c;
        float t = (v[c]-mu)*rs*P.ln1_w[cc]+P.ln1_b[cc];
        xo[(size_t)c*NP] = t;
        xnsh[p][cc] = t;
      }
      __syncthreads();
      float vv[32];
#pragma unroll
      for (int c=0;c<32;c++) vv[c]=xnsh[p][c];
      float a = P.sq1_b[sl];
#pragma unroll
      for (int c=0;c<32;c++) a += vv[c]*P.sq1_w[sl*32+c];
      P.z1[(size_t)b*8*NP + (size_t)sl*NP + n] = a;
      __syncthreads();
    }
  }
  gsync(P.bar, 0, GRID);

  // ---------------- Phase B: cab1 (576) || sq2 (144). 720 units ----------------
  {
    float (*red5)[5] = (float(*)[5])smem;                // [4][5]
    for (int u_=blockIdx.x; u_<720; u_+=G){
      if (u_ < 576){
        int og = u_/72, pb = u_%72;
        int idx = pb*256+tid;
        int b = idx/NP, n = idx%NP, i = n/96, j = n%96;
        const float* xb = P.xn + (size_t)b*32*NP;
        const float* wb = P.cab_w1 + og*288;
        int o_[9]; float m_[9]; int d=0;
#pragma unroll
        for (int di=0;di<3;di++){
          int ii=i+di-1; bool vi = (unsigned)ii<96u;
#pragma unroll
          for (int dj=0;dj<3;dj++){
            int jj=j+dj-1; bool vld = vi && ((unsigned)jj<96u);
            o_[d] = vld ? ii*96+jj : 0; m_[d] = vld ? 1.f : 0.f; d++;
          }
        }
        float accd[9] = {0,0,0,0,0,0,0,0,0};
        for (int c=0;c<32;c++){
          const float* xp = xb + (size_t)c*NP;
          const float* wp = wb + c*9;
          float t[9];
#pragma unroll
          for (int d2=0;d2<9;d2++) t[d2] = xp[o_[d2]];
#pragma unroll
          for (int d2=0;d2<9;d2++) accd[d2] += t[d2]*wp[d2];
        }
        float acc = P.cab_b1[og];
#pragma unroll
        for (int d2=0;d2<9;d2++) acc += accd[d2]*m_[d2];
        P.c1b[(size_t)b*8*NP + (size_t)og*NP + n] = gelu_ex(acc);
      } else {
        int u2 = u_-576;
        int pr = u2/18, pb = u2%18;
        int idx = pb*256+tid;
        int b = idx/NP2, n = idx%NP2, i = n/48, j = n%48;
        int ocA = pr, ocB = pr+8;
        int gA = ocA>>1, gB = ocB>>1;
        const float* zpA = P.z1 + ((size_t)b*8+gA)*NP + (size_t)(2*i)*96 + 2*j;
        const float* zpB = P.z1 + ((size_t)b*8+gB)*NP + (size_t)(2*i)*96 + 2*j;
        const float* w = P.sq2_w;
        float vA = zpA[0]*w[ocA*4]+zpA[1]*w[ocA*4+1]+zpA[96]*w[ocA*4+2]+zpA[97]*w[ocA*4+3]+P.sq2_b[ocA];
        float vB = zpB[0]*w[ocB*4]+zpB[1]*w[ocB*4+1]+zpB[96]*w[ocB*4+2]+zpB[97]*w[ocB*4+3]+P.sq2_b[ocB];
        P.u[((size_t)b*16+2*pr)*NP2 + n]   = vA;
        P.u[((size_t)b*16+2*pr+1)*NP2 + n] = vB;
        int wv=tid>>6, ln=tid&63;
        float st[5]={vA,vB,vA*vA,vB*vB,vA*vB};
#pragma unroll
        for (int k=0;k<5;k++){
          float r=st[k];
#pragma unroll
          for (int m=1;m<64;m<<=1) r+=__shfl_xor(r,m,64);
          if (ln==0) red5[wv][k]=r;
        }
        __syncthreads();
        if (tid<5){
          float r = red5[0][tid]+red5[1][tid]+red5[2][tid]+red5[3][tid];
          P.spart[(b*9 + (pb%9))*40 + pr*5 + tid] = r;
        }
        __syncthreads();
      }
    }
  }
  gsync(P.bar, 1, GRID);

  // ---------------- Phase C: cab2 (576) || qkmom (288). 864 units ----------------
  {
    for (int u_=blockIdx.x; u_<864; u_+=G){
      if (u_ < 576){
        float (*red4)[4] = (float(*)[4])smem;            // [4][4]
        int og = u_/72, pb = u_%72;
        int idx = pb*256+tid;
        int b = idx/NP, n = idx%NP, i = n/96, j = n%96;
        int o_[9]; float m_[9]; int d=0;
#pragma unroll
        for (int di=0;di<3;di++){
          int ii=i+di-1; bool vi = (unsigned)ii<96u;
#pragma unroll
          for (int dj=0;dj<3;dj++){
            int jj=j+dj-1; bool vld = vi && ((unsigned)jj<96u);
            o_[d] = vld ? ii*96+jj : 0; m_[d] = vld ? 1.f : 0.f; d++;
          }
        }
        float acc[4];
#pragma unroll
        for (int k=0;k<4;k++) acc[k]=P.cab_b2[og*4+k];
        const float* cbp = P.c1b + (size_t)b*8*NP;
        for (int c=0;c<8;c++){
          const float* xp = cbp + (size_t)c*NP;
          float t[9];
#pragma unroll
          for (int d2=0;d2<9;d2++) t[d2] = xp[o_[d2]]*m_[d2];
#pragma unroll
          for (int k=0;k<4;k++){
            const float* wp = P.cab_w2 + (og*4+k)*72 + c*9;
#pragma unroll
            for (int d2=0;d2<9;d2++) acc[k] += t[d2]*wp[d2];
          }
        }
        int wv = tid>>6, ln = tid&63;
#pragma unroll
        for (int k=0;k<4;k++){
          P.cb[(size_t)b*32*NP + (size_t)(og*4+k)*NP + n] = acc[k];
          float r = acc[k];
#pragma unroll
          for (int m=1;m<64;m<<=1) r += __shfl_xor(r, m, 64);
          if (ln==0) red4[wv][k]=r;
        }
        __syncthreads();
        if (tid<4){
          float r = red4[0][tid]+red4[1][tid]+red4[2][tid]+red4[3][tid];
          P.ypart[(og*72+pb)*4 + tid] = r;
        }
        __syncthreads();
      } else {
        float (*red16)[80] = (float(*)[80])smem;         // [16][80]
        int u2 = u_-576;
        int bh = u2/9, ch = u2%9;
        int n = ch*256 + tid;
        int b = bh>>4, h = bh&15;
        int p = h&7, s = h>>3;
        int cc0=2*p, cc1=2*p+1;
        int oc0 = 2*(cc0&7)+(cc0>>3);
        int oc1 = 2*(cc1&7)+(cc1>>3);
        float AA[2], BB[2], CCc[2];
#pragma unroll
        for (int t2=0;t2<2;t2++){
          int oc = t2? oc1:oc0;
          int p2 = oc>>1, dd = oc&1;
          float st[5]={0,0,0,0,0};
          for (int ib=0; ib<9; ib++){
#pragma unroll
            for (int k=0;k<5;k++) st[k] += P.spart[(b*9+ib)*40 + p2*5 + k];
          }
          float S0=st[0],S1=st[1],Q00=st[2],Q11=st[3],Q01=st[4];
          float Sd = dd? S1:S0;
          float Qdd = dd? Q11:Q00;
          float cu0[2],cu1[2],ccst[2];
#pragma unroll
          for (int hh=0;hh<2;hh++){
            int h2=p2+8*hh;
            float th2=P.ca_t[h2];
            float aq=P.ca_qkv_w[(2*p2+dd)*6+hh], bq=P.ca_qkv_b[(2*p2+dd)*6+hh];
            float nq=fmaxf(sqrtf(fmaxf(aq*aq*Qdd+2.f*aq*bq*Sd+2304.f*bq*bq,0.f)),1e-12f);
            float m2[2],av[2],bv[2];
#pragma unroll
            for (int e=0;e<2;e++){
              float Se_=e?S1:S0, Qee=e?Q11:Q00, Qde=(dd==e)?Qdd:Q01;
              float ak=P.ca_qkv_w[(2*p2+e)*6+2+hh], bk=P.ca_qkv_b[(2*p2+e)*6+2+hh];
              float nk=fmaxf(sqrtf(fmaxf(ak*ak*Qee+2.f*ak*bk*Se_+2304.f*bk*bk,0.f)),1e-12f);
              float D=aq*ak*Qde + aq*bk*Sd + bq*ak*Se_ + 2304.f*bq*bk;
              m2[e]=th2*D/(nq*nk);
              av[e]=P.ca_qkv_w[(2*p2+e)*6+4+hh]; bv[e]=P.ca_qkv_b[(2*p2+e)*6+4+hh];
            }
            float mx=fmaxf(m2[0],m2[1]);
            float e0=__expf(m2[0]-mx), e1=__expf(m2[1]-mx);
            float inv=1.f/(e0+e1);
            cu0[hh]=e0*inv*av[0]; cu1[hh]=e1*inv*av[1]; ccst[hh]=e0*inv*bv[0]+e1*inv*bv[1];
          }
          float f0=P.ca_fus_w[oc*2], f1=P.ca_fus_w[oc*2+1];
          AA[t2]=f0*cu0[0]+f1*cu0[1];
          BB[t2]=f0*cu1[0]+f1*cu1[1];
          CCc[t2]=f0*ccst[0]+f1*ccst[1]+P.ca_fus_b[oc];
        }
        const float* u00 = P.u + ((size_t)b*16 + (oc0>>1)*2)*NP2;
        const float* u01 = u00 + NP2;
        const float* u10 = P.u + ((size_t)b*16 + (oc1>>1)*2)*NP2;
        const float* u11 = u10 + NP2;
        float w0 = AA[0]*u00[n]+BB[0]*u01[n]+CCc[0];
        float w1 = AA[1]*u10[n]+BB[1]*u11[n]+CCc[1];
        float k0 = P.sa_qkv_w[cc0*6+2+s]*w0+P.sa_qkv_b[cc0*6+2+s];
        float k1 = P.sa_qkv_w[cc1*6+2+s]*w1+P.sa_qkv_b[cc1*6+2+s];
        float rnk = 1.f/fmaxf(sqrtf(k0*k0+k1*k1),1e-12f);
        float kc = k0*rnk, ks = k1*rnk;
        float q0 = P.sa_qkv_w[cc0*6+s]*w0+P.sa_qkv_b[cc0*6+s];
        float q1 = P.sa_qkv_w[cc1*6+s]*w1+P.sa_qkv_b[cc1*6+s];
        float rnq = 1.f/fmaxf(sqrtf(q0*q0+q1*q1),1e-12f);
        P.qarr[bh*NP2+n] = make_float2(q0*rnq, q1*rnq);

        int grp = tid>>4, gl = tid&15;
        float c = 1.f, sn = 0.f;
#pragma unroll
        for (int k=0;k<=KH;k++){
          float vals[6] = {c, sn, c*w0, sn*w0, c*w1, sn*w1};
#pragma unroll
          for (int jv=0;jv<6;jv++){
            float r = vals[jv];
            r += __shfl_xor(r, 1, 64);
            r += __shfl_xor(r, 2, 64);
            r += __shfl_xor(r, 4, 64);
            r += __shfl_xor(r, 8, 64);
            if (gl==0) red16[grp][k*6+jv] = r;
          }
          float cn = c*kc - sn*ks;
          sn = sn*kc + c*ks;
          c = cn;
        }
        __syncthreads();
        if (tid < NMOM){
          float r = 0.f;
#pragma unroll
          for (int g=0;g<16;g++) r += red16[g][tid];
          P.mompart[(bh*9+ch)*NMOM + tid] = r;
        }
        __syncthreads();
      }
    }
  }
  gsync(P.bar, 2, GRID);

  // ---------------- Phase D: rows (144 units) ----------------
  {
    float (*msh)[80] = (float(*)[80])smem;               // [2][80]
    float (*fsh)[13] = (float(*)[13])(smem+160);         // [2][13]
    for (int u_=blockIdx.x; u_<144; u_+=G){
      int bp = u_/9, ch = u_%9;
      int b = bp>>3, p = bp&7;
      int n = ch*256 + tid;
      if (tid < 26){
        int hh = tid/13, k = tid%13;
        double t = (double)P.sa_t[p+8*hh];
        double fac;
        if (fabs(t) < 1e-3){
          double xh = 0.5*t;
          double pk = 1.0;
          for (int q=1;q<=k;q++) pk *= xh/(double)q;
          double Ik = pk*(1.0 + xh*xh/(double)(k+1));
          fac = (k? 2.0:1.0)*Ik;
        } else {
          const int KS = 36;
          double ip1 = 0.0, ik = 1e-280, sum2 = 0.0;
          double vk = 0.0, v0 = 0.0;
          for (int q=KS; q>=1; --q){
            if (q == k) vk = ik;
            sum2 += ik;
            double im1 = ip1 + (2.0*(double)q/t)*ik;
            ip1 = ik; ik = im1;
          }
          v0 = ik;
          if (k == 0) vk = v0;
          double total = v0 + 2.0*sum2;
          double scale = exp(t)/total;
          fac = (k? 2.0:1.0)*vk*scale;
        }
        fsh[hh][k] = (float)fac;
      }
      if (tid < 2*NMOM){
        int hh = tid/NMOM, jj = tid%NMOM;
        float ssum = 0.f;
        for (int ib=0; ib<9; ib++)
          ssum += P.mompart[((size_t)(b*16+p+8*hh)*9+ib)*NMOM + jj];
        msh[hh][jj] = ssum;
      }
      __syncthreads();
      if (tid < 2*NMOM){
        int hh = tid/NMOM, jj = tid%NMOM;
        msh[hh][jj] *= fsh[hh][jj/6];
      }
      __syncthreads();
      float o[2][2];
#pragma unroll
      for (int hh=0;hh<2;hh++){
        float2 q = P.qarr[(size_t)(b*16+p+8*hh)*NP2 + n];
        float c = 1.f, sn = 0.f;
        float Se=0.f, S0=0.f, S1=0.f;
#pragma unroll
        for (int k=0;k<=KH;k++){
          const float* mk = &msh[hh][k*6];
          Se += c*mk[0] + sn*mk[1];
          S0 += c*mk[2] + sn*mk[3];
          S1 += c*mk[4] + sn*mk[5];
          float cn = c*q.x - sn*q.y;
          sn = sn*q.x + c*q.y;
          c = cn;
        }
        float rSe = 1.f/Se;
        float av0=P.sa_qkv_w[(2*p)*6+4+hh],  bv0=P.sa_qkv_b[(2*p)*6+4+hh];
        float av1=P.sa_qkv_w[(2*p+1)*6+4+hh],bv1=P.sa_qkv_b[(2*p+1)*6+4+hh];
        o[hh][0]=av0*S0*rSe+bv0;
        o[hh][1]=av1*S1*rSe+bv1;
      }
      float zz0 = o[0][0]*P.sa_fus_w[(2*p)*2]   + o[1][0]*P.sa_fus_w[(2*p)*2+1]   + P.sa_fus_b[2*p];
      float zz1 = o[0][1]*P.sa_fus_w[(2*p+1)*2] + o[1][1]*P.sa_fus_w[(2*p+1)*2+1] + P.sa_fus_b[2*p+1];
      int i=n/48, j=n%48;
      float* pb2 = P.psb + ((size_t)b*8+p)*NP;
#pragma unroll
      for (int k=0;k<4;k++){
        int od = 4*p+k;
        float v = zz0*P.un1_w[od*2] + zz1*P.un1_w[od*2+1] + P.un1_b[od];
        pb2[(size_t)(2*i+(k>>1))*96 + 2*j + (k&1)] = v;
      }
      __syncthreads();
    }
  }
  gsync(P.bar, 3, GRID);

  // ---------------- Phase E: SE + un2 + residual + LN2 + da_w1 (576 units) ----------------
  {
    float (*sred)[8][32] = (float(*)[8][32])smem;        // [2][8][32]
    float (*xsh)[33]     = (float(*)[33])(smem+512);     // [32][33]
    float *y2sh          = smem+1568;                    // [32]
    for (int u_=blockIdx.x; u_<576; u_+=G){
      int p = tid & 31, sl = tid >> 5;
      int pix = u_*32 + p;
      int b = pix/NP, n = pix%NP;
      if (tid < 32){
        int c = tid;
        float ssum = 0.f;
        for (int ib=0; ib<36; ib++)
          ssum += P.ypart[((c>>2)*72 + b*36 + ib)*4 + (c&3)];
        float pr = ssum*(1.f/9216.f)*P.cab_aw1[c];
#pragma unroll
        for (int m=1;m<32;m<<=1) pr += __shfl_xor(pr, m, 64);
        float y1 = fmaxf(pr+P.cab_ab1[0], 0.f);
        y2sh[c] = sigm(P.cab_aw2[c]*y1+P.cab_ab2[c]);
      }
      float pg[8];
#pragma unroll
      for (int g=0;g<8;g++) pg[g]=P.psb[((size_t)b*8+g)*NP+n];
      __syncthreads();
      float xv[4]; float s=0.f,s2=0.f;
#pragma unroll
      for (int c=0;c<4;c++){
        int cc = sl*4+c;
        float a=P.un2_b[cc];
#pragma unroll
        for (int g=0;g<8;g++) a+=pg[g]*P.un2_w[cc*8+g];
        size_t off=((size_t)b*32+cc)*NP+n;
        float t = P.x[off]+a+P.cb[off]*y2sh[cc];
        xv[c]=t; P.xsm[off]=t; s+=t; s2+=t*t;
      }
      sred[0][sl][p]=s; sred[1][sl][p]=s2;
      __syncthreads();
      s=0.f; s2=0.f;
#pragma unroll
      for (int g=0;g<8;g++){ s += sred[0][g][p]; s2 += sred[1][g][p]; }
      float mu=s*(1.f/32.f), var=s2*(1.f/32.f)-mu*mu, rs=rsqrtf(var+1e-5f);
#pragma unroll
      for (int c=0;c<4;c++){
        int cc = sl*4+c;
        xsh[p][cc] = (xv[c]-mu)*rs*P.ln2_w[cc]+P.ln2_b[cc];
      }
      __syncthreads();
      float vv[32];
#pragma unroll
      for (int c=0;c<32;c++) vv[c]=xsh[p][c];
#pragma unroll
      for (int k=0;k<4;k++){
        int o = sl*4+k;
        float a=P.da_b1[o];
#pragma unroll
        for (int cc=0;cc<32;cc++) a+=vv[cc]*P.da_w1[o*32+cc];
        P.d1[((size_t)b*32+o)*NP+n]=a;
      }
      __syncthreads();
    }
  }
  gsync(P.bar, 4, GRID);

  // ---------------- Phase F: 7x7 depthwise gate (1152 units) ----------------
  {
    for (int u_=blockIdx.x; u_<1152; u_+=G){
      int idx = u_*256+tid;
      int pl = idx/4608, n2 = idx%4608;
      int i2 = n2/96, j = n2%96;
      int c = pl&31;
      const float* dp = P.d1 + (size_t)pl*NP;
      const float* w0p = P.da_dw_w + (2*c)*49;
      const float* w1p = P.da_dw_w + (2*c+1)*49;
      float a0=P.da_dw_b[2*c], a1=P.da_dw_b[2*c+1];
      float c0=P.da_dw_b[2*c], c1=P.da_dw_b[2*c+1];
#pragma unroll
      for (int di=0;di<8;di++){
        int ii=2*i2-3+di; if ((unsigned)ii>=96u) continue;
        const float* rowp = dp + ii*96;
        float t[7];
#pragma unroll
        for (int dj=0;dj<7;dj++){
          int jj=j+dj-3;
          t[dj] = ((unsigned)jj<96u) ? rowp[jj] : 0.f;
        }
        if (di<7){
#pragma unroll
          for (int dj=0;dj<7;dj++){ a0 += t[dj]*w0p[di*7+dj]; a1 += t[dj]*w1p[di*7+dj]; }
        }
        if (di>0){
#pragma unroll
          for (int dj=0;dj<7;dj++){ c0 += t[dj]*w0p[(di-1)*7+dj]; c1 += t[dj]*w1p[(di-1)*7+dj]; }
        }
      }
      P.dg[(size_t)pl*NP + (size_t)(2*i2)*96 + j]   = gelu_ex(a0)*sigm(a1);
      P.dg[(size_t)pl*NP + (size_t)(2*i2+1)*96 + j] = gelu_ex(c0)*sigm(c1);
    }
  }
  gsync(P.bar, 5, GRID);

  // ---------------- Phase G: final 1x1 conv + residual -> out (288 units) ----------------
  {
    float (*xsh)[33] = (float(*)[33])smem;               // [64][33]
    for (int u_=blockIdx.x; u_<288; u_+=G){
      int p = tid & 63, sl = tid >> 6;
      int pix = u_*64 + p;
      int b = pix/NP, n = pix%NP;
      const float* dp = P.dg + ((size_t)b*32 + sl*8)*NP + n;
#pragma unroll
      for (int c=0;c<8;c++) xsh[p][sl*8+c]=dp[(size_t)c*NP];
      __syncthreads();
      float vv[32];
#pragma unroll
      for (int c=0;c<32;c++) vv[c]=xsh[p][c];
#pragma unroll
      for (int k=0;k<8;k++){
        int o = sl*8+k;
        float a=P.da_pb[o];
#pragma unroll
        for (int cc=0;cc<32;cc++) a+=vv[cc]*P.da_pw[o*32+cc];
        size_t off=((size_t)b*32+o)*NP+n;
        P.out[off]=P.xsm[off]+a;
      }
      __syncthreads();
    }
  }
}

extern "C" void kernel_launch(void* const* d_in, const int* in_sizes, int n_in,
                              void* d_out, int out_size, void* d_ws, size_t ws_size,
                              hipStream_t stream) {
  (void)in_sizes; (void)n_in; (void)out_size; (void)ws_size;
  float* ws=(float*)d_ws;
  MParams mp;
  mp.x        =(const float*)d_in[0];
  mp.cab_w1   =(const float*)d_in[1];
  mp.cab_w2   =(const float*)d_in[2];
  mp.cab_aw1  =(const float*)d_in[3];
  mp.cab_aw2  =(const float*)d_in[4];
  mp.sq1_w    =(const float*)d_in[5];
  mp.sq2_w    =(const float*)d_in[6];
  mp.ca_qkv_w =(const float*)d_in[7];
  mp.ca_fus_w =(const float*)d_in[8];
  mp.sa_qkv_w =(const float*)d_in[9];
  mp.sa_fus_w =(const float*)d_in[10];
  mp.un1_w    =(const float*)d_in[11];
  mp.un2_w    =(const float*)d_in[12];
  mp.da_w1    =(const float*)d_in[13];
  mp.da_dw_w  =(const float*)d_in[14];
  mp.da_pw    =(const float*)d_in[15];
  mp.cab_b1   =(const float*)d_in[16];
  mp.cab_b2   =(const float*)d_in[17];
  mp.cab_ab1  =(const float*)d_in[18];
  mp.cab_ab2  =(const float*)d_in[19];
  mp.sq1_b    =(const float*)d_in[20];
  mp.sq2_b    =(const float*)d_in[21];
  mp.ca_qkv_b =(const float*)d_in[22];
  mp.ca_fus_b =(const float*)d_in[23];
  mp.sa_qkv_b =(const float*)d_in[24];
  mp.sa_fus_b =(const float*)d_in[25];
  mp.un1_b    =(const float*)d_in[26];
  mp.un2_b    =(const float*)d_in[27];
  mp.da_b1    =(const float*)d_in[28];
  mp.da_dw_b  =(const float*)d_in[29];
  mp.da_pb    =(const float*)d_in[30];
  mp.ln1_w    =(const float*)d_in[31];
  mp.ln1_b    =(const float*)d_in[32];
  mp.ln2_w    =(const float*)d_in[33];
  mp.ln2_b    =(const float*)d_in[34];
  mp.ca_t     =(const float*)d_in[35];
  mp.sa_t     =(const float*)d_in[36];

  mp.xn     = ws;               // 589824 (reused as d1 after phase B)
  mp.z1     = ws + 589824;      // 147456
  mp.c1b    = ws + 737280;      // 147456
  mp.cb     = ws + 884736;      // 589824 (cbuf; reused as dg after phase E)
  mp.u      = ws + 1474560;     // 73728
  mp.psb    = ws + 1548288;     // 147456
  mp.xsm    = ws + 1695744;     // 589824
  mp.ypart  = ws + 2285568;     // 2304
  mp.spart  = ws + 2294784;     // 720 (+pad)
  mp.qarr   = (float2*)(ws + 2295552);  // 147456 floats
  mp.mompart= ws + 2443008;     // 22464
  mp.d1     = mp.xn;            // alias: xn dead after phase B
  mp.dg     = mp.cb;            // alias: cb dead after phase E
  mp.out    = (float*)d_out;
  mp.bar    = (unsigned*)(ws + 2465472);  // 6 slots x 64 u32

  hipMemsetAsync((void*)mp.bar, 0, 6*64*sizeof(unsigned), stream);
  mega<<<GRID, 256, 0, stream>>>(mp);
}

// Round 12
// 229.116 us; speedup vs baseline: 2.6646x; 1.5327x over previous
//
#include <hip/hip_runtime.h>
#include <cstdint>
#include <math.h>

#define NP 9216     // 96*96
#define NP2 2304    // 48*48
#define KH 12       // harmonics k=0..12
#define NMOM 78     // 13 * 6
#define GRID 512
#define SLOT 4128   // uints per barrier slot: (64 gcnt + 1 root + 64 gflag) * 32

__device__ __forceinline__ float gelu_ex(float v){
  return 0.5f*v*(1.0f+erff(v*0.70710678118654752440f));
}
__device__ __forceinline__ float sigm(float v){
  return 1.0f/(1.0f+__expf(-v));
}

// Hierarchical one-shot grid barrier: 64 groups x 8 blocks.
// Max fan-in per cache line = 64 (root) vs 512 flat -> no poll-queue blowup.
// Slots zeroed by captured hipMemsetAsync before each launch.
__device__ __forceinline__ void gsync(unsigned* bar, int slot){
  __syncthreads();
  if (threadIdx.x==0){
    __threadfence();                      // release: write back this XCD's L2
    unsigned* base  = bar + slot*SLOT;
    int g = blockIdx.x >> 3, rk = blockIdx.x & 7;
    unsigned* gcnt  = base + g*32;
    unsigned* root  = base + 64*32;
    unsigned* gflag = base + (65+g)*32;
    __hip_atomic_fetch_add(gcnt, 1u, __ATOMIC_RELAXED, __HIP_MEMORY_SCOPE_AGENT);
    if (rk==0){
      while (__hip_atomic_load(gcnt, __ATOMIC_RELAXED, __HIP_MEMORY_SCOPE_AGENT) < 8u)
        __builtin_amdgcn_s_sleep(1);
      __hip_atomic_fetch_add(root, 1u, __ATOMIC_RELAXED, __HIP_MEMORY_SCOPE_AGENT);
      while (__hip_atomic_load(root, __ATOMIC_RELAXED, __HIP_MEMORY_SCOPE_AGENT) < 64u)
        __builtin_amdgcn_s_sleep(8);
      __hip_atomic_store(gflag, 1u, __ATOMIC_RELAXED, __HIP_MEMORY_SCOPE_AGENT);
    } else {
      while (!__hip_atomic_load(gflag, __ATOMIC_RELAXED, __HIP_MEMORY_SCOPE_AGENT))
        __builtin_amdgcn_s_sleep(4);
    }
    __threadfence();                      // acquire: invalidate stale lines
  }
  __syncthreads();
}

struct MParams {
  const float *x;
  const float *cab_w1,*cab_w2,*cab_aw1,*cab_aw2,*sq1_w,*sq2_w,*ca_qkv_w,*ca_fus_w;
  const float *sa_qkv_w,*sa_fus_w,*un1_w,*un2_w,*da_w1,*da_dw_w,*da_pw;
  const float *cab_b1,*cab_b2,*cab_ab1,*cab_ab2,*sq1_b,*sq2_b,*ca_qkv_b,*ca_fus_b;
  const float *sa_qkv_b,*sa_fus_b,*un1_b,*un2_b,*da_b1,*da_dw_b,*da_pb;
  const float *ln1_w,*ln1_b,*ln2_w,*ln2_b,*ca_t,*sa_t;
  float *xn,*z1,*c1b,*cb,*u,*psb,*xsm,*ypart,*spart,*mompart;
  float2 *qarr;
  float *d1,*dg,*out;
  unsigned *bar;
};

__global__ __launch_bounds__(256,2) void mega(MParams P)
{
  __shared__ float smem[2112];   // 8448 B union across phases
  const int G = gridDim.x;
  const int tid = threadIdx.x;

  // ---------------- Phase A: channel-LN + sq1 1x1 (32->8). 576 units ----------------
  {
    float (*sred)[8][32] = (float(*)[8][32])smem;        // [2][8][32]
    float (*xnsh)[33]    = (float(*)[33])(smem+512);     // [32][33]
    for (int u_=blockIdx.x; u_<576; u_+=G){
      int p = tid & 31, sl = tid >> 5;
      int pix = u_*32 + p;
      int b = pix / NP, n = pix % NP;
      const float* xp = P.x + (size_t)b*32*NP + (size_t)(sl*4)*NP + n;
      float v[4]; float s=0.f, s2=0.f;
#pragma unroll
      for (int c=0;c<4;c++){ float t=xp[(size_t)c*NP]; v[c]=t; s+=t; s2+=t*t; }
      sred[0][sl][p]=s; sred[1][sl][p]=s2;
      __syncthreads();
      s=0.f; s2=0.f;
#pragma unroll
      for (int g=0;g<8;g++){ s += sred[0][g][p]; s2 += sred[1][g][p]; }
      float mu = s*(1.f/32.f);
      float var = s2*(1.f/32.f)-mu*mu;
      float rs = rsqrtf(var+1e-5f);
      float* xo = P.xn + (size_t)b*32*NP + (size_t)(sl*4)*NP + n;
#pragma unroll
      for (int c=0;c<4;c++){
        int cc = sl*4+c;
        float t = (v[c]-mu)*rs*P.ln1_w[cc]+P.ln1_b[cc];
        xo[(size_t)c*NP] = t;
        xnsh[p][cc] = t;
      }
      __syncthreads();
      float vv[32];
#pragma unroll
      for (int c=0;c<32;c++) vv[c]=xnsh[p][c];
      float a = P.sq1_b[sl];
#pragma unroll
      for (int c=0;c<32;c++) a += vv[c]*P.sq1_w[sl*32+c];
      P.z1[(size_t)b*8*NP + (size_t)sl*NP + n] = a;
      __syncthreads();
    }
  }
  gsync(P.bar, 0);

  // ---------------- Phase B: cab1 (576) || sq2 (144). 720 units ----------------
  {
    float (*red5)[5] = (float(*)[5])smem;                // [4][5]
    for (int u_=blockIdx.x; u_<720; u_+=G){
      if (u_ < 576){
        int og = u_/72, pb = u_%72;
        int idx = pb*256+tid;
        int b = idx/NP, n = idx%NP, i = n/96, j = n%96;
        const float* xb = P.xn + (size_t)b*32*NP;
        const float* wb = P.cab_w1 + og*288;
        int o_[9]; float m_[9]; int d=0;
#pragma unroll
        for (int di=0;di<3;di++){
          int ii=i+di-1; bool vi = (unsigned)ii<96u;
#pragma unroll
          for (int dj=0;dj<3;dj++){
            int jj=j+dj-1; bool vld = vi && ((unsigned)jj<96u);
            o_[d] = vld ? ii*96+jj : 0; m_[d] = vld ? 1.f : 0.f; d++;
          }
        }
        float accd[9] = {0,0,0,0,0,0,0,0,0};
        for (int c=0;c<32;c++){
          const float* xp = xb + (size_t)c*NP;
          const float* wp = wb + c*9;
          float t[9];
#pragma unroll
          for (int d2=0;d2<9;d2++) t[d2] = xp[o_[d2]];
#pragma unroll
          for (int d2=0;d2<9;d2++) accd[d2] += t[d2]*wp[d2];
        }
        float acc = P.cab_b1[og];
#pragma unroll
        for (int d2=0;d2<9;d2++) acc += accd[d2]*m_[d2];
        P.c1b[(size_t)b*8*NP + (size_t)og*NP + n] = gelu_ex(acc);
      } else {
        int u2 = u_-576;
        int pr = u2/18, pb = u2%18;
        int idx = pb*256+tid;
        int b = idx/NP2, n = idx%NP2, i = n/48, j = n%48;
        int ocA = pr, ocB = pr+8;
        int gA = ocA>>1, gB = ocB>>1;
        const float* zpA = P.z1 + ((size_t)b*8+gA)*NP + (size_t)(2*i)*96 + 2*j;
        const float* zpB = P.z1 + ((size_t)b*8+gB)*NP + (size_t)(2*i)*96 + 2*j;
        const float* w = P.sq2_w;
        float vA = zpA[0]*w[ocA*4]+zpA[1]*w[ocA*4+1]+zpA[96]*w[ocA*4+2]+zpA[97]*w[ocA*4+3]+P.sq2_b[ocA];
        float vB = zpB[0]*w[ocB*4]+zpB[1]*w[ocB*4+1]+zpB[96]*w[ocB*4+2]+zpB[97]*w[ocB*4+3]+P.sq2_b[ocB];
        P.u[((size_t)b*16+2*pr)*NP2 + n]   = vA;
        P.u[((size_t)b*16+2*pr+1)*NP2 + n] = vB;
        int wv=tid>>6, ln=tid&63;
        float st[5]={vA,vB,vA*vA,vB*vB,vA*vB};
#pragma unroll
        for (int k=0;k<5;k++){
          float r=st[k];
#pragma unroll
          for (int m=1;m<64;m<<=1) r+=__shfl_xor(r,m,64);
          if (ln==0) red5[wv][k]=r;
        }
        __syncthreads();
        if (tid<5){
          float r = red5[0][tid]+red5[1][tid]+red5[2][tid]+red5[3][tid];
          P.spart[(b*9 + (pb%9))*40 + pr*5 + tid] = r;
        }
        __syncthreads();
      }
    }
  }
  gsync(P.bar, 1);

  // ---------------- Phase C: cab2 (576) || qkmom (288). 864 units ----------------
  {
    for (int u_=blockIdx.x; u_<864; u_+=G){
      if (u_ < 576){
        float (*red4)[4] = (float(*)[4])smem;            // [4][4]
        int og = u_/72, pb = u_%72;
        int idx = pb*256+tid;
        int b = idx/NP, n = idx%NP, i = n/96, j = n%96;
        int o_[9]; float m_[9]; int d=0;
#pragma unroll
        for (int di=0;di<3;di++){
          int ii=i+di-1; bool vi = (unsigned)ii<96u;
#pragma unroll
          for (int dj=0;dj<3;dj++){
            int jj=j+dj-1; bool vld = vi && ((unsigned)jj<96u);
            o_[d] = vld ? ii*96+jj : 0; m_[d] = vld ? 1.f : 0.f; d++;
          }
        }
        float acc[4];
#pragma unroll
        for (int k=0;k<4;k++) acc[k]=P.cab_b2[og*4+k];
        const float* cbp = P.c1b + (size_t)b*8*NP;
        for (int c=0;c<8;c++){
          const float* xp = cbp + (size_t)c*NP;
          float t[9];
#pragma unroll
          for (int d2=0;d2<9;d2++) t[d2] = xp[o_[d2]]*m_[d2];
#pragma unroll
          for (int k=0;k<4;k++){
            const float* wp = P.cab_w2 + (og*4+k)*72 + c*9;
#pragma unroll
            for (int d2=0;d2<9;d2++) acc[k] += t[d2]*wp[d2];
          }
        }
        int wv = tid>>6, ln = tid&63;
#pragma unroll
        for (int k=0;k<4;k++){
          P.cb[(size_t)b*32*NP + (size_t)(og*4+k)*NP + n] = acc[k];
          float r = acc[k];
#pragma unroll
          for (int m=1;m<64;m<<=1) r += __shfl_xor(r, m, 64);
          if (ln==0) red4[wv][k]=r;
        }
        __syncthreads();
        if (tid<4){
          float r = red4[0][tid]+red4[1][tid]+red4[2][tid]+red4[3][tid];
          P.ypart[(og*72+pb)*4 + tid] = r;
        }
        __syncthreads();
      } else {
        float (*red16)[80] = (float(*)[80])smem;         // [16][80]
        int u2 = u_-576;
        int bh = u2/9, ch = u2%9;
        int n = ch*256 + tid;
        int b = bh>>4, h = bh&15;
        int p = h&7, s = h>>3;
        int cc0=2*p, cc1=2*p+1;
        int oc0 = 2*(cc0&7)+(cc0>>3);
        int oc1 = 2*(cc1&7)+(cc1>>3);
        float AA[2], BB[2], CCc[2];
#pragma unroll
        for (int t2=0;t2<2;t2++){
          int oc = t2? oc1:oc0;
          int p2 = oc>>1, dd = oc&1;
          float st[5]={0,0,0,0,0};
          for (int ib=0; ib<9; ib++){
#pragma unroll
            for (int k=0;k<5;k++) st[k] += P.spart[(b*9+ib)*40 + p2*5 + k];
          }
          float S0=st[0],S1=st[1],Q00=st[2],Q11=st[3],Q01=st[4];
          float Sd = dd? S1:S0;
          float Qdd = dd? Q11:Q00;
          float cu0[2],cu1[2],ccst[2];
#pragma unroll
          for (int hh=0;hh<2;hh++){
            int h2=p2+8*hh;
            float th2=P.ca_t[h2];
            float aq=P.ca_qkv_w[(2*p2+dd)*6+hh], bq=P.ca_qkv_b[(2*p2+dd)*6+hh];
            float nq=fmaxf(sqrtf(fmaxf(aq*aq*Qdd+2.f*aq*bq*Sd+2304.f*bq*bq,0.f)),1e-12f);
            float m2[2],av[2],bv[2];
#pragma unroll
            for (int e=0;e<2;e++){
              float Se_=e?S1:S0, Qee=e?Q11:Q00, Qde=(dd==e)?Qdd:Q01;
              float ak=P.ca_qkv_w[(2*p2+e)*6+2+hh], bk=P.ca_qkv_b[(2*p2+e)*6+2+hh];
              float nk=fmaxf(sqrtf(fmaxf(ak*ak*Qee+2.f*ak*bk*Se_+2304.f*bk*bk,0.f)),1e-12f);
              float D=aq*ak*Qde + aq*bk*Sd + bq*ak*Se_ + 2304.f*bq*bk;
              m2[e]=th2*D/(nq*nk);
              av[e]=P.ca_qkv_w[(2*p2+e)*6+4+hh]; bv[e]=P.ca_qkv_b[(2*p2+e)*6+4+hh];
            }
            float mx=fmaxf(m2[0],m2[1]);
            float e0=__expf(m2[0]-mx), e1=__expf(m2[1]-mx);
            float inv=1.f/(e0+e1);
            cu0[hh]=e0*inv*av[0]; cu1[hh]=e1*inv*av[1]; ccst[hh]=e0*inv*bv[0]+e1*inv*bv[1];
          }
          float f0=P.ca_fus_w[oc*2], f1=P.ca_fus_w[oc*2+1];
          AA[t2]=f0*cu0[0]+f1*cu0[1];
          BB[t2]=f0*cu1[0]+f1*cu1[1];
          CCc[t2]=f0*ccst[0]+f1*ccst[1]+P.ca_fus_b[oc];
        }
        const float* u00 = P.u + ((size_t)b*16 + (oc0>>1)*2)*NP2;
        const float* u01 = u00 + NP2;
        const float* u10 = P.u + ((size_t)b*16 + (oc1>>1)*2)*NP2;
        const float* u11 = u10 + NP2;
        float w0 = AA[0]*u00[n]+BB[0]*u01[n]+CCc[0];
        float w1 = AA[1]*u10[n]+BB[1]*u11[n]+CCc[1];
        float k0 = P.sa_qkv_w[cc0*6+2+s]*w0+P.sa_qkv_b[cc0*6+2+s];
        float k1 = P.sa_qkv_w[cc1*6+2+s]*w1+P.sa_qkv_b[cc1*6+2+s];
        float rnk = 1.f/fmaxf(sqrtf(k0*k0+k1*k1),1e-12f);
        float kc = k0*rnk, ks = k1*rnk;
        float q0 = P.sa_qkv_w[cc0*6+s]*w0+P.sa_qkv_b[cc0*6+s];
        float q1 = P.sa_qkv_w[cc1*6+s]*w1+P.sa_qkv_b[cc1*6+s];
        float rnq = 1.f/fmaxf(sqrtf(q0*q0+q1*q1),1e-12f);
        P.qarr[bh*NP2+n] = make_float2(q0*rnq, q1*rnq);

        int grp = tid>>4, gl = tid&15;
        float c = 1.f, sn = 0.f;
#pragma unroll
        for (int k=0;k<=KH;k++){
          float vals[6] = {c, sn, c*w0, sn*w0, c*w1, sn*w1};
#pragma unroll
          for (int jv=0;jv<6;jv++){
            float r = vals[jv];
            r += __shfl_xor(r, 1, 64);
            r += __shfl_xor(r, 2, 64);
            r += __shfl_xor(r, 4, 64);
            r += __shfl_xor(r, 8, 64);
            if (gl==0) red16[grp][k*6+jv] = r;
          }
          float cn = c*kc - sn*ks;
          sn = sn*kc + c*ks;
          c = cn;
        }
        __syncthreads();
        if (tid < NMOM){
          float r = 0.f;
#pragma unroll
          for (int g=0;g<16;g++) r += red16[g][tid];
          P.mompart[(bh*9+ch)*NMOM + tid] = r;
        }
        __syncthreads();
      }
    }
  }
  gsync(P.bar, 2);

  // ---------------- Phase D: rows (144 units) ----------------
  {
    float (*msh)[80] = (float(*)[80])smem;               // [2][80]
    float (*fsh)[13] = (float(*)[13])(smem+160);         // [2][13]
    for (int u_=blockIdx.x; u_<144; u_+=G){
      int bp = u_/9, ch = u_%9;
      int b = bp>>3, p = bp&7;
      int n = ch*256 + tid;
      if (tid < 26){
        int hh = tid/13, k = tid%13;
        double t = (double)P.sa_t[p+8*hh];
        double fac;
        if (fabs(t) < 1e-3){
          double xh = 0.5*t;
          double pk = 1.0;
          for (int q=1;q<=k;q++) pk *= xh/(double)q;
          double Ik = pk*(1.0 + xh*xh/(double)(k+1));
          fac = (k? 2.0:1.0)*Ik;
        } else {
          const int KS = 36;
          double ip1 = 0.0, ik = 1e-280, sum2 = 0.0;
          double vk = 0.0, v0 = 0.0;
          for (int q=KS; q>=1; --q){
            if (q == k) vk = ik;
            sum2 += ik;
            double im1 = ip1 + (2.0*(double)q/t)*ik;
            ip1 = ik; ik = im1;
          }
          v0 = ik;
          if (k == 0) vk = v0;
          double total = v0 + 2.0*sum2;
          double scale = exp(t)/total;
          fac = (k? 2.0:1.0)*vk*scale;
        }
        fsh[hh][k] = (float)fac;
      }
      if (tid < 2*NMOM){
        int hh = tid/NMOM, jj = tid%NMOM;
        float ssum = 0.f;
        for (int ib=0; ib<9; ib++)
          ssum += P.mompart[((size_t)(b*16+p+8*hh)*9+ib)*NMOM + jj];
        msh[hh][jj] = ssum;
      }
      __syncthreads();
      if (tid < 2*NMOM){
        int hh = tid/NMOM, jj = tid%NMOM;
        msh[hh][jj] *= fsh[hh][jj/6];
      }
      __syncthreads();
      float o[2][2];
#pragma unroll
      for (int hh=0;hh<2;hh++){
        float2 q = P.qarr[(size_t)(b*16+p+8*hh)*NP2 + n];
        float c = 1.f, sn = 0.f;
        float Se=0.f, S0=0.f, S1=0.f;
#pragma unroll
        for (int k=0;k<=KH;k++){
          const float* mk = &msh[hh][k*6];
          Se += c*mk[0] + sn*mk[1];
          S0 += c*mk[2] + sn*mk[3];
          S1 += c*mk[4] + sn*mk[5];
          float cn = c*q.x - sn*q.y;
          sn = sn*q.x + c*q.y;
          c = cn;
        }
        float rSe = 1.f/Se;
        float av0=P.sa_qkv_w[(2*p)*6+4+hh],  bv0=P.sa_qkv_b[(2*p)*6+4+hh];
        float av1=P.sa_qkv_w[(2*p+1)*6+4+hh],bv1=P.sa_qkv_b[(2*p+1)*6+4+hh];
        o[hh][0]=av0*S0*rSe+bv0;
        o[hh][1]=av1*S1*rSe+bv1;
      }
      float zz0 = o[0][0]*P.sa_fus_w[(2*p)*2]   + o[1][0]*P.sa_fus_w[(2*p)*2+1]   + P.sa_fus_b[2*p];
      float zz1 = o[0][1]*P.sa_fus_w[(2*p+1)*2] + o[1][1]*P.sa_fus_w[(2*p+1)*2+1] + P.sa_fus_b[2*p+1];
      int i=n/48, j=n%48;
      float* pb2 = P.psb + ((size_t)b*8+p)*NP;
#pragma unroll
      for (int k=0;k<4;k++){
        int od = 4*p+k;
        float v = zz0*P.un1_w[od*2] + zz1*P.un1_w[od*2+1] + P.un1_b[od];
        pb2[(size_t)(2*i+(k>>1))*96 + 2*j + (k&1)] = v;
      }
      __syncthreads();
    }
  }
  gsync(P.bar, 3);

  // ---------------- Phase E: SE + un2 + residual + LN2 + da_w1 (576 units) ----------------
  {
    float (*sred)[8][32] = (float(*)[8][32])smem;        // [2][8][32]
    float (*xsh)[33]     = (float(*)[33])(smem+512);     // [32][33]
    float *y2sh          = smem+1568;                    // [32]
    for (int u_=blockIdx.x; u_<576; u_+=G){
      int p = tid & 31, sl = tid >> 5;
      int pix = u_*32 + p;
      int b = pix/NP, n = pix%NP;
      if (tid < 32){
        int c = tid;
        float ssum = 0.f;
        for (int ib=0; ib<36; ib++)
          ssum += P.ypart[((c>>2)*72 + b*36 + ib)*4 + (c&3)];
        float pr = ssum*(1.f/9216.f)*P.cab_aw1[c];
#pragma unroll
        for (int m=1;m<32;m<<=1) pr += __shfl_xor(pr, m, 64);
        float y1 = fmaxf(pr+P.cab_ab1[0], 0.f);
        y2sh[c] = sigm(P.cab_aw2[c]*y1+P.cab_ab2[c]);
      }
      float pg[8];
#pragma unroll
      for (int g=0;g<8;g++) pg[g]=P.psb[((size_t)b*8+g)*NP+n];
      __syncthreads();
      float xv[4]; float s=0.f,s2=0.f;
#pragma unroll
      for (int c=0;c<4;c++){
        int cc = sl*4+c;
        float a=P.un2_b[cc];
#pragma unroll
        for (int g=0;g<8;g++) a+=pg[g]*P.un2_w[cc*8+g];
        size_t off=((size_t)b*32+cc)*NP+n;
        float t = P.x[off]+a+P.cb[off]*y2sh[cc];
        xv[c]=t; P.xsm[off]=t; s+=t; s2+=t*t;
      }
      sred[0][sl][p]=s; sred[1][sl][p]=s2;
      __syncthreads();
      s=0.f; s2=0.f;
#pragma unroll
      for (int g=0;g<8;g++){ s += sred[0][g][p]; s2 += sred[1][g][p]; }
      float mu=s*(1.f/32.f), var=s2*(1.f/32.f)-mu*mu, rs=rsqrtf(var+1e-5f);
#pragma unroll
      for (int c=0;c<4;c++){
        int cc = sl*4+c;
        xsh[p][cc] = (xv[c]-mu)*rs*P.ln2_w[cc]+P.ln2_b[cc];
      }
      __syncthreads();
      float vv[32];
#pragma unroll
      for (int c=0;c<32;c++) vv[c]=xsh[p][c];
#pragma unroll
      for (int k=0;k<4;k++){
        int o = sl*4+k;
        float a=P.da_b1[o];
#pragma unroll
        for (int cc=0;cc<32;cc++) a+=vv[cc]*P.da_w1[o*32+cc];
        P.d1[((size_t)b*32+o)*NP+n]=a;
      }
      __syncthreads();
    }
  }
  gsync(P.bar, 4);

  // ---------------- Phase F: 7x7 depthwise gate (1152 units) ----------------
  {
    for (int u_=blockIdx.x; u_<1152; u_+=G){
      int idx = u_*256+tid;
      int pl = idx/4608, n2 = idx%4608;
      int i2 = n2/96, j = n2%96;
      int c = pl&31;
      const float* dp = P.d1 + (size_t)pl*NP;
      const float* w0p = P.da_dw_w + (2*c)*49;
      const float* w1p = P.da_dw_w + (2*c+1)*49;
      float a0=P.da_dw_b[2*c], a1=P.da_dw_b[2*c+1];
      float c0=P.da_dw_b[2*c], c1=P.da_dw_b[2*c+1];
#pragma unroll
      for (int di=0;di<8;di++){
        int ii=2*i2-3+di; if ((unsigned)ii>=96u) continue;
        const float* rowp = dp + ii*96;
        float t[7];
#pragma unroll
        for (int dj=0;dj<7;dj++){
          int jj=j+dj-3;
          t[dj] = ((unsigned)jj<96u) ? rowp[jj] : 0.f;
        }
        if (di<7){
#pragma unroll
          for (int dj=0;dj<7;dj++){ a0 += t[dj]*w0p[di*7+dj]; a1 += t[dj]*w1p[di*7+dj]; }
        }
        if (di>0){
#pragma unroll
          for (int dj=0;dj<7;dj++){ c0 += t[dj]*w0p[(di-1)*7+dj]; c1 += t[dj]*w1p[(di-1)*7+dj]; }
        }
      }
      P.dg[(size_t)pl*NP + (size_t)(2*i2)*96 + j]   = gelu_ex(a0)*sigm(a1);
      P.dg[(size_t)pl*NP + (size_t)(2*i2+1)*96 + j] = gelu_ex(c0)*sigm(c1);
    }
  }
  gsync(P.bar, 5);

  // ---------------- Phase G: final 1x1 conv + residual -> out (288 units) ----------------
  {
    float (*xsh)[33] = (float(*)[33])smem;               // [64][33]
    for (int u_=blockIdx.x; u_<288; u_+=G){
      int p = tid & 63, sl = tid >> 6;
      int pix = u_*64 + p;
      int b = pix/NP, n = pix%NP;
      const float* dp = P.dg + ((size_t)b*32 + sl*8)*NP + n;
#pragma unroll
      for (int c=0;c<8;c++) xsh[p][sl*8+c]=dp[(size_t)c*NP];
      __syncthreads();
      float vv[32];
#pragma unroll
      for (int c=0;c<32;c++) vv[c]=xsh[p][c];
#pragma unroll
      for (int k=0;k<8;k++){
        int o = sl*8+k;
        float a=P.da_pb[o];
#pragma unroll
        for (int cc=0;cc<32;cc++) a+=vv[cc]*P.da_pw[o*32+cc];
        size_t off=((size_t)b*32+o)*NP+n;
        P.out[off]=P.xsm[off]+a;
      }
      __syncthreads();
    }
  }
}

extern "C" void kernel_launch(void* const* d_in, const int* in_sizes, int n_in,
                              void* d_out, int out_size, void* d_ws, size_t ws_size,
                              hipStream_t stream) {
  (void)in_sizes; (void)n_in; (void)out_size; (void)ws_size;
  float* ws=(float*)d_ws;
  MParams mp;
  mp.x        =(const float*)d_in[0];
  mp.cab_w1   =(const float*)d_in[1];
  mp.cab_w2   =(const float*)d_in[2];
  mp.cab_aw1  =(const float*)d_in[3];
  mp.cab_aw2  =(const float*)d_in[4];
  mp.sq1_w    =(const float*)d_in[5];
  mp.sq2_w    =(const float*)d_in[6];
  mp.ca_qkv_w =(const float*)d_in[7];
  mp.ca_fus_w =(const float*)d_in[8];
  mp.sa_qkv_w =(const float*)d_in[9];
  mp.sa_fus_w =(const float*)d_in[10];
  mp.un1_w    =(const float*)d_in[11];
  mp.un2_w    =(const float*)d_in[12];
  mp.da_w1    =(const float*)d_in[13];
  mp.da_dw_w  =(const float*)d_in[14];
  mp.da_pw    =(const float*)d_in[15];
  mp.cab_b1   =(const float*)d_in[16];
  mp.cab_b2   =(const float*)d_in[17];
  mp.cab_ab1  =(const float*)d_in[18];
  mp.cab_ab2  =(const float*)d_in[19];
  mp.sq1_b    =(const float*)d_in[20];
  mp.sq2_b    =(const float*)d_in[21];
  mp.ca_qkv_b =(const float*)d_in[22];
  mp.ca_fus_b =(const float*)d_in[23];
  mp.sa_qkv_b =(const float*)d_in[24];
  mp.sa_fus_b =(const float*)d_in[25];
  mp.un1_b    =(const float*)d_in[26];
  mp.un2_b    =(const float*)d_in[27];
  mp.da_b1    =(const float*)d_in[28];
  mp.da_dw_b  =(const float*)d_in[29];
  mp.da_pb    =(const float*)d_in[30];
  mp.ln1_w    =(const float*)d_in[31];
  mp.ln1_b    =(const float*)d_in[32];
  mp.ln2_w    =(const float*)d_in[33];
  mp.ln2_b    =(const float*)d_in[34];
  mp.ca_t     =(const float*)d_in[35];
  mp.sa_t     =(const float*)d_in[36];

  mp.xn     = ws;               // 589824 (reused as d1 after phase B)
  mp.z1     = ws + 589824;      // 147456
  mp.c1b    = ws + 737280;      // 147456
  mp.cb     = ws + 884736;      // 589824 (cbuf; reused as dg after phase E)
  mp.u      = ws + 1474560;     // 73728
  mp.psb    = ws + 1548288;     // 147456
  mp.xsm    = ws + 1695744;     // 589824
  mp.ypart  = ws + 2285568;     // 2304
  mp.spart  = ws + 2294784;     // 720 (+pad)
  mp.qarr   = (float2*)(ws + 2295552);  // 147456 floats
  mp.mompart= ws + 2443008;     // 22464
  mp.d1     = mp.xn;            // alias: xn dead after phase B
  mp.dg     = mp.cb;            // alias: cb dead after phase E
  mp.out    = (float*)d_out;
  mp.bar    = (unsigned*)(ws + 2465472);  // 6 slots x 4128 u32 = 99 KB

  hipMemsetAsync((void*)mp.bar, 0, 6*SLOT*sizeof(unsigned), stream);
  mega<<<GRID, 256, 0, stream>>>(mp);
}

// Round 13
// 71.588 us; speedup vs baseline: 8.5281x; 3.2005x over previous
//
#include <hip/hip_runtime.h>
#include <cstdint>
#include <math.h>

#define NP 9216     // 96*96
#define NP2 2304    // 48*48
#define KH 12       // harmonics k=0..12 (I_13(1)~1e-12: exact in fp32)
#define NMOM 78     // 13 * 6

__device__ __forceinline__ float gelu_ex(float v){
  return 0.5f*v*(1.0f+erff(v*0.70710678118654752440f));
}
__device__ __forceinline__ float sigm(float v){
  return 1.0f/(1.0f+__expf(-v));
}

// K1: channel-LN over C=32 per pixel + sq1 1x1 conv (32->8)
// block = 32 px x 8 slices (4 ch each); grid = 576
__global__ __launch_bounds__(256) void k_ln1(const float* __restrict__ x,
    const float* __restrict__ lw, const float* __restrict__ lb,
    const float* __restrict__ sw, const float* __restrict__ sb,
    float* __restrict__ xn, float* __restrict__ z1)
{
  __shared__ float sred[2][8][32];
  __shared__ float xnsh[32][33];
  int p = threadIdx.x & 31, sl = threadIdx.x >> 5;
  int pix = blockIdx.x*32 + p;
  int b = pix / NP, n = pix % NP;
  const float* xp = x + (size_t)b*32*NP + (size_t)(sl*4)*NP + n;
  float v[4]; float s=0.f, s2=0.f;
#pragma unroll
  for (int c=0;c<4;c++){ float t=xp[(size_t)c*NP]; v[c]=t; s+=t; s2+=t*t; }
  sred[0][sl][p]=s; sred[1][sl][p]=s2;
  __syncthreads();
  s=0.f; s2=0.f;
#pragma unroll
  for (int g=0;g<8;g++){ s += sred[0][g][p]; s2 += sred[1][g][p]; }
  float mu = s*(1.f/32.f);
  float var = s2*(1.f/32.f)-mu*mu;
  float rs = rsqrtf(var+1e-5f);
  float* xo = xn + (size_t)b*32*NP + (size_t)(sl*4)*NP + n;
#pragma unroll
  for (int c=0;c<4;c++){
    int cc = sl*4+c;
    float t = (v[c]-mu)*rs*lw[cc]+lb[cc];
    xo[(size_t)c*NP] = t;
    xnsh[p][cc] = t;
  }
  __syncthreads();
  float vv[32];
#pragma unroll
  for (int c=0;c<32;c++) vv[c]=xnsh[p][c];
  int g = sl;
  float a = sb[g];
#pragma unroll
  for (int c=0;c<32;c++) a += vv[c]*sw[g*32+c];
  z1[(size_t)b*8*NP + (size_t)g*NP + n] = a;
}

// Phase B: cab1 (blocks 0..575, og-split 3x3 conv 32->8 + GELU)
//       || sq2  (blocks 576..719, stride-2 2x2 grouped conv + IDX permute + stats)
__global__ __launch_bounds__(256) void k_phB(const float* __restrict__ xn,
    const float* __restrict__ w1, const float* __restrict__ b1,
    const float* __restrict__ z1, const float* __restrict__ w2,
    const float* __restrict__ b2,
    float* __restrict__ c1, float* __restrict__ u, float* __restrict__ spart)
{
  if (blockIdx.x < 576){
    int og = blockIdx.x/72, pb = blockIdx.x%72;
    int idx = pb*256+threadIdx.x;
    int b = idx/NP, n = idx%NP, i = n/96, j = n%96;
    float acc = b1[og];
    const float* xb = xn + (size_t)b*32*NP;
    const float* wb = w1 + og*288;
#pragma unroll
    for (int di=0;di<3;di++){
      int ii=i+di-1; if ((unsigned)ii>=96u) continue;
#pragma unroll
      for (int dj=0;dj<3;dj++){
        int jj=j+dj-1; if ((unsigned)jj>=96u) continue;
        const float* xp = xb + ii*96+jj;
        const float* wp = wb + di*3+dj;
#pragma unroll
        for (int c=0;c<32;c++) acc += xp[(size_t)c*NP]*wp[c*9];
      }
    }
    c1[(size_t)b*8*NP + (size_t)og*NP + n] = gelu_ex(acc);
  } else {
    __shared__ float red[4][5];
    int u2 = blockIdx.x-576;
    int pr = u2/18, pb = u2%18;
    int idx = pb*256+threadIdx.x;
    int b = idx/NP2, n = idx%NP2, i = n/48, j = n%48;
    int ocA = pr, ocB = pr+8;           // cp = 2*pr, 2*pr+1
    int gA = ocA>>1, gB = ocB>>1;
    const float* zpA = z1 + ((size_t)b*8+gA)*NP + (size_t)(2*i)*96 + 2*j;
    const float* zpB = z1 + ((size_t)b*8+gB)*NP + (size_t)(2*i)*96 + 2*j;
    float vA = zpA[0]*w2[ocA*4]+zpA[1]*w2[ocA*4+1]+zpA[96]*w2[ocA*4+2]+zpA[97]*w2[ocA*4+3]+b2[ocA];
    float vB = zpB[0]*w2[ocB*4]+zpB[1]*w2[ocB*4+1]+zpB[96]*w2[ocB*4+2]+zpB[97]*w2[ocB*4+3]+b2[ocB];
    u[((size_t)b*16+2*pr)*NP2 + n]   = vA;
    u[((size_t)b*16+2*pr+1)*NP2 + n] = vB;
    int wv=threadIdx.x>>6, ln=threadIdx.x&63;
    float st[5]={vA,vB,vA*vA,vB*vB,vA*vB};
#pragma unroll
    for (int k=0;k<5;k++){
      float r=st[k];
#pragma unroll
      for (int m=1;m<64;m<<=1) r+=__shfl_xor(r,m,64);
      if (ln==0) red[wv][k]=r;
    }
    __syncthreads();
    if (threadIdx.x<5){
      float r = red[0][threadIdx.x]+red[1][threadIdx.x]+red[2][threadIdx.x]+red[3][threadIdx.x];
      spart[(b*9 + (pb%9))*40 + pr*5 + threadIdx.x] = r;
    }
  }
}

// Phase C: cab2 (blocks 0..575, og-split 3x3 conv 8->32 + SE partials)
//       || qkmom (blocks 576..863, q-hat + Fourier moments, inline coef collapse)
__global__ __launch_bounds__(256) void k_phC(const float* __restrict__ c1,
    const float* __restrict__ w2, const float* __restrict__ b2,
    float* __restrict__ cbuf, float* __restrict__ ypart,
    const float* __restrict__ u, const float* __restrict__ spart,
    const float* __restrict__ cqw, const float* __restrict__ cqb,
    const float* __restrict__ cat, const float* __restrict__ cfw,
    const float* __restrict__ cfb,
    const float* __restrict__ qw, const float* __restrict__ qb,
    float2* __restrict__ qarr, float* __restrict__ mompart)
{
  if (blockIdx.x < 576){
    __shared__ float red[4][4];
    int og = blockIdx.x/72, pb = blockIdx.x%72;
    int idx = pb*256+threadIdx.x;
    int b = idx/NP, n = idx%NP, i = n/96, j = n%96;
    float acc[4];
#pragma unroll
    for (int k=0;k<4;k++) acc[k]=b2[og*4+k];
    const float* cb = c1 + (size_t)b*8*NP;
#pragma unroll
    for (int di=0;di<3;di++){
      int ii=i+di-1; if ((unsigned)ii>=96u) continue;
#pragma unroll
      for (int dj=0;dj<3;dj++){
        int jj=j+dj-1; if ((unsigned)jj>=96u) continue;
        const float* xp = cb + ii*96+jj;
#pragma unroll
        for (int c=0;c<8;c++){
          float val = xp[(size_t)c*NP];
          const float* wp = w2 + (og*4)*72 + c*9+di*3+dj;
#pragma unroll
          for (int k=0;k<4;k++) acc[k] += val*wp[k*72];
        }
      }
    }
    int wv = threadIdx.x>>6, ln = threadIdx.x&63;
#pragma unroll
    for (int k=0;k<4;k++){
      cbuf[(size_t)b*32*NP + (size_t)(og*4+k)*NP + n] = acc[k];
      float r = acc[k];
#pragma unroll
      for (int m=1;m<64;m<<=1) r += __shfl_xor(r, m, 64);
      if (ln==0) red[wv][k]=r;
    }
    __syncthreads();
    if (threadIdx.x<4){
      float r = red[0][threadIdx.x]+red[1][threadIdx.x]+red[2][threadIdx.x]+red[3][threadIdx.x];
      ypart[(og*72+pb)*4 + threadIdx.x] = r;
    }
  } else {
    __shared__ float red16[16][80];
    int u2 = blockIdx.x-576;
    int bh = u2/9, ch = u2%9;
    int n = ch*256 + threadIdx.x;
    int b = bh>>4, h = bh&15;
    int p = h&7, s = h>>3;
    int cc0=2*p, cc1=2*p+1;
    int oc0 = 2*(cc0&7)+(cc0>>3);   // NIDX
    int oc1 = 2*(cc1&7)+(cc1>>3);
    float AA[2], BB[2], CCc[2];
#pragma unroll
    for (int t2=0;t2<2;t2++){
      int oc = t2? oc1:oc0;
      int p2 = oc>>1, dd = oc&1;
      float st[5]={0,0,0,0,0};
      for (int ib=0; ib<9; ib++){
#pragma unroll
        for (int k=0;k<5;k++) st[k] += spart[(b*9+ib)*40 + p2*5 + k];
      }
      float S0=st[0],S1=st[1],Q00=st[2],Q11=st[3],Q01=st[4];
      float Sd = dd? S1:S0;
      float Qdd = dd? Q11:Q00;
      float cu0[2],cu1[2],ccst[2];
#pragma unroll
      for (int hh=0;hh<2;hh++){
        int h2=p2+8*hh;
        float th2=cat[h2];
        float aq=cqw[(2*p2+dd)*6+hh], bq=cqb[(2*p2+dd)*6+hh];
        float nq=fmaxf(sqrtf(fmaxf(aq*aq*Qdd+2.f*aq*bq*Sd+2304.f*bq*bq,0.f)),1e-12f);
        float m2[2],av[2],bv[2];
#pragma unroll
        for (int e=0;e<2;e++){
          float Se_=e?S1:S0, Qee=e?Q11:Q00, Qde=(dd==e)?Qdd:Q01;
          float ak=cqw[(2*p2+e)*6+2+hh], bk=cqb[(2*p2+e)*6+2+hh];
          float nk=fmaxf(sqrtf(fmaxf(ak*ak*Qee+2.f*ak*bk*Se_+2304.f*bk*bk,0.f)),1e-12f);
          float D=aq*ak*Qde + aq*bk*Sd + bq*ak*Se_ + 2304.f*bq*bk;
          m2[e]=th2*D/(nq*nk);
          av[e]=cqw[(2*p2+e)*6+4+hh]; bv[e]=cqb[(2*p2+e)*6+4+hh];
        }
        float mx=fmaxf(m2[0],m2[1]);
        float e0=__expf(m2[0]-mx), e1=__expf(m2[1]-mx);
        float inv=1.f/(e0+e1);
        cu0[hh]=e0*inv*av[0]; cu1[hh]=e1*inv*av[1]; ccst[hh]=e0*inv*bv[0]+e1*inv*bv[1];
      }
      float f0=cfw[oc*2], f1=cfw[oc*2+1];
      AA[t2]=f0*cu0[0]+f1*cu0[1];
      BB[t2]=f0*cu1[0]+f1*cu1[1];
      CCc[t2]=f0*ccst[0]+f1*ccst[1]+cfb[oc];
    }
    const float* u00 = u + ((size_t)b*16 + (oc0>>1)*2)*NP2;
    const float* u01 = u00 + NP2;
    const float* u10 = u + ((size_t)b*16 + (oc1>>1)*2)*NP2;
    const float* u11 = u10 + NP2;
    float w0 = AA[0]*u00[n]+BB[0]*u01[n]+CCc[0];
    float w1 = AA[1]*u10[n]+BB[1]*u11[n]+CCc[1];
    float k0 = qw[cc0*6+2+s]*w0+qb[cc0*6+2+s];
    float k1 = qw[cc1*6+2+s]*w1+qb[cc1*6+2+s];
    float rnk = 1.f/fmaxf(sqrtf(k0*k0+k1*k1),1e-12f);
    float kc = k0*rnk, ks = k1*rnk;      // (cos beta, sin beta)
    float q0 = qw[cc0*6+s]*w0+qb[cc0*6+s];
    float q1 = qw[cc1*6+s]*w1+qb[cc1*6+s];
    float rnq = 1.f/fmaxf(sqrtf(q0*q0+q1*q1),1e-12f);
    qarr[bh*NP2+n] = make_float2(q0*rnq, q1*rnq);

    int grp = threadIdx.x>>4, gl = threadIdx.x&15;
    float c = 1.f, sn = 0.f;
#pragma unroll
    for (int k=0;k<=KH;k++){
      float vals[6] = {c, sn, c*w0, sn*w0, c*w1, sn*w1};
#pragma unroll
      for (int jv=0;jv<6;jv++){
        float r = vals[jv];
        r += __shfl_xor(r, 1, 64);
        r += __shfl_xor(r, 2, 64);
        r += __shfl_xor(r, 4, 64);
        r += __shfl_xor(r, 8, 64);
        if (gl==0) red16[grp][k*6+jv] = r;
      }
      float cn = c*kc - sn*ks;
      sn = sn*kc + c*ks;
      c = cn;
    }
    __syncthreads();
    if (threadIdx.x < NMOM){
      float r = 0.f;
#pragma unroll
      for (int g=0;g<16;g++) r += red16[g][threadIdx.x];
      mompart[(bh*9+ch)*NMOM + threadIdx.x] = r;
    }
  }
}

// K7: combine moment chunks, Bessel factors, per-row Fourier eval, softmax finish,
// v-affine, spat fuse conv, un1 grouped conv, pixel-shuffle write. grid 144.
__global__ __launch_bounds__(256) void k_rows(const float2* __restrict__ qarr,
    const float* __restrict__ mompart, const float* __restrict__ sat,
    const float* __restrict__ qw, const float* __restrict__ qb,
    const float* __restrict__ fw, const float* __restrict__ fb,
    const float* __restrict__ u1w, const float* __restrict__ u1b,
    float* __restrict__ ps)
{
  int bp = blockIdx.x/9, ch = blockIdx.x%9;
  int b = bp>>3, p = bp&7;
  int n = ch*256 + (int)threadIdx.x;
  __shared__ float msh[2][80];
  __shared__ float fsh[2][13];
  int tid = threadIdx.x;
  if (tid < 26){
    int hh = tid/13, k = tid%13;
    double t = (double)sat[p+8*hh];
    double fac;
    if (fabs(t) < 1e-3){
      double xh = 0.5*t;
      double pk = 1.0;
      for (int q=1;q<=k;q++) pk *= xh/(double)q;
      double Ik = pk*(1.0 + xh*xh/(double)(k+1));
      fac = (k? 2.0:1.0)*Ik;
    } else {
      const int KS = 36;
      double ip1 = 0.0, ik = 1e-280, sum2 = 0.0;
      double vk = 0.0, v0 = 0.0;
      for (int q=KS; q>=1; --q){
        if (q == k) vk = ik;
        sum2 += ik;
        double im1 = ip1 + (2.0*(double)q/t)*ik;
        ip1 = ik; ik = im1;
      }
      v0 = ik;
      if (k == 0) vk = v0;
      double total = v0 + 2.0*sum2;
      double scale = exp(t)/total;
      fac = (k? 2.0:1.0)*vk*scale;
    }
    fsh[hh][k] = (float)fac;
  }
  if (tid < 2*NMOM){
    int hh = tid/NMOM, jj = tid%NMOM;
    float ssum = 0.f;
    for (int ib=0; ib<9; ib++)
      ssum += mompart[((size_t)(b*16+p+8*hh)*9+ib)*NMOM + jj];
    msh[hh][jj] = ssum;
  }
  __syncthreads();
  if (tid < 2*NMOM){
    int hh = tid/NMOM, jj = tid%NMOM;
    msh[hh][jj] *= fsh[hh][jj/6];
  }
  __syncthreads();
  float o[2][2];
#pragma unroll
  for (int hh=0;hh<2;hh++){
    float2 q = qarr[(size_t)(b*16+p+8*hh)*NP2 + n];
    float c = 1.f, sn = 0.f;
    float Se=0.f, S0=0.f, S1=0.f;
#pragma unroll
    for (int k=0;k<=KH;k++){
      const float* mk = &msh[hh][k*6];
      Se += c*mk[0] + sn*mk[1];
      S0 += c*mk[2] + sn*mk[3];
      S1 += c*mk[4] + sn*mk[5];
      float cn = c*q.x - sn*q.y;
      sn = sn*q.x + c*q.y;
      c = cn;
    }
    float rSe = 1.f/Se;
    float av0=qw[(2*p)*6+4+hh],  bv0=qb[(2*p)*6+4+hh];
    float av1=qw[(2*p+1)*6+4+hh],bv1=qb[(2*p+1)*6+4+hh];
    o[hh][0]=av0*S0*rSe+bv0;
    o[hh][1]=av1*S1*rSe+bv1;
  }
  float zz0 = o[0][0]*fw[(2*p)*2]   + o[1][0]*fw[(2*p)*2+1]   + fb[2*p];
  float zz1 = o[0][1]*fw[(2*p+1)*2] + o[1][1]*fw[(2*p+1)*2+1] + fb[2*p+1];
  int i=n/48, j=n%48;
  float* pb2 = ps + ((size_t)b*8+p)*NP;
#pragma unroll
  for (int k=0;k<4;k++){
    int od = 4*p+k;
    float v = zz0*u1w[od*2] + zz1*u1w[od*2+1] + u1b[od];
    pb2[(size_t)(2*i+(k>>1))*96 + 2*j + (k&1)] = v;
  }
}

// K9: inline SE + un2 1x1 (8->32) + residual + LN2 + da_w1 1x1 (32->32)
// block = 32 px x 8 slices (4 ch each); grid = 576
__global__ __launch_bounds__(256) void k_un2(const float* __restrict__ ps,
    const float* __restrict__ ypart,
    const float* __restrict__ aw1, const float* __restrict__ ab1,
    const float* __restrict__ aw2, const float* __restrict__ ab2,
    const float* __restrict__ u2w, const float* __restrict__ u2b,
    const float* __restrict__ x, const float* __restrict__ cbuf,
    const float* __restrict__ lw, const float* __restrict__ lb,
    const float* __restrict__ dw1, const float* __restrict__ db1,
    float* __restrict__ xsum, float* __restrict__ d1)
{
  __shared__ float sred[2][8][32];
  __shared__ float xsh[32][33];
  __shared__ float y2sh[32];
  int p = threadIdx.x & 31, sl = threadIdx.x >> 5;
  int pix = blockIdx.x*32 + p;
  int b = pix/NP, n = pix%NP;
  if (threadIdx.x < 32){
    int c = threadIdx.x;
    float ssum = 0.f;
    for (int ib=0; ib<36; ib++)
      ssum += ypart[((c>>2)*72 + b*36 + ib)*4 + (c&3)];
    float pr = ssum*(1.f/9216.f)*aw1[c];
#pragma unroll
    for (int m=1;m<32;m<<=1) pr += __shfl_xor(pr, m, 64);
    float y1 = fmaxf(pr+ab1[0], 0.f);
    y2sh[c] = sigm(aw2[c]*y1+ab2[c]);
  }
  float pg[8];
#pragma unroll
  for (int g=0;g<8;g++) pg[g]=ps[((size_t)b*8+g)*NP+n];
  __syncthreads();
  float xv[4]; float s=0.f,s2=0.f;
#pragma unroll
  for (int c=0;c<4;c++){
    int cc = sl*4+c;
    float a=u2b[cc];
#pragma unroll
    for (int g=0;g<8;g++) a+=pg[g]*u2w[cc*8+g];
    size_t off=((size_t)b*32+cc)*NP+n;
    float t = x[off]+a+cbuf[off]*y2sh[cc];
    xv[c]=t; xsum[off]=t; s+=t; s2+=t*t;
  }
  sred[0][sl][p]=s; sred[1][sl][p]=s2;
  __syncthreads();
  s=0.f; s2=0.f;
#pragma unroll
  for (int g=0;g<8;g++){ s += sred[0][g][p]; s2 += sred[1][g][p]; }
  float mu=s*(1.f/32.f), var=s2*(1.f/32.f)-mu*mu, rs=rsqrtf(var+1e-5f);
#pragma unroll
  for (int c=0;c<4;c++){
    int cc = sl*4+c;
    xsh[p][cc] = (xv[c]-mu)*rs*lw[cc]+lb[cc];
  }
  __syncthreads();
  float vv[32];
#pragma unroll
  for (int c=0;c<32;c++) vv[c]=xsh[p][c];
#pragma unroll
  for (int k=0;k<4;k++){
    int o = sl*4+k;
    float a=db1[o];
#pragma unroll
    for (int cc=0;cc<32;cc++) a+=vv[cc]*dw1[o*32+cc];
    d1[((size_t)b*32+o)*NP+n]=a;
  }
}

// K10: 7x7 depthwise conv (2 filters/channel), 2 vertical px/thread, + gate
__global__ __launch_bounds__(256) void k_dw(const float* __restrict__ d1,
    const float* __restrict__ w, const float* __restrict__ bias,
    float* __restrict__ dg)
{
  int idx = blockIdx.x*256+threadIdx.x;   // 64 planes * 4608
  int pl = idx/4608, n2 = idx%4608;
  int i2 = n2/96, j = n2%96;
  int c = pl&31;
  const float* dp = d1 + (size_t)pl*NP;
  const float* w0p = w + (2*c)*49;
  const float* w1p = w + (2*c+1)*49;
  float a0=bias[2*c], a1=bias[2*c+1];
  float c0=bias[2*c], c1=bias[2*c+1];
#pragma unroll
  for (int di=0;di<8;di++){
    int ii=2*i2-3+di; if ((unsigned)ii>=96u) continue;
    const float* rowp = dp + ii*96;
    float t[7];
#pragma unroll
    for (int dj=0;dj<7;dj++){
      int jj=j+dj-3;
      t[dj] = ((unsigned)jj<96u) ? rowp[jj] : 0.f;
    }
    if (di<7){
#pragma unroll
      for (int dj=0;dj<7;dj++){ a0 += t[dj]*w0p[di*7+dj]; a1 += t[dj]*w1p[di*7+dj]; }
    }
    if (di>0){
#pragma unroll
      for (int dj=0;dj<7;dj++){ c0 += t[dj]*w0p[(di-1)*7+dj]; c1 += t[dj]*w1p[(di-1)*7+dj]; }
    }
  }
  dg[(size_t)pl*NP + (size_t)(2*i2)*96 + j]   = gelu_ex(a0)*sigm(a1);
  dg[(size_t)pl*NP + (size_t)(2*i2+1)*96 + j] = gelu_ex(c0)*sigm(c1);
}

// K11: final 1x1 conv (32->32) + residual -> d_out. block = 32 px x 8 slices; grid 576
__global__ __launch_bounds__(256) void k_fin(const float* __restrict__ dg,
    const float* __restrict__ pw, const float* __restrict__ pb,
    const float* __restrict__ xsum, float* __restrict__ out)
{
  __shared__ float xsh[32][33];
  int p = threadIdx.x & 31, sl = threadIdx.x >> 5;
  int pix = blockIdx.x*32 + p;
  int b = pix/NP, n = pix%NP;
  const float* dp = dg + ((size_t)b*32 + sl*4)*NP + n;
#pragma unroll
  for (int c=0;c<4;c++) xsh[p][sl*4+c]=dp[(size_t)c*NP];
  __syncthreads();
  float vv[32];
#pragma unroll
  for (int c=0;c<32;c++) vv[c]=xsh[p][c];
#pragma unroll
  for (int k=0;k<4;k++){
    int o = sl*4+k;
    float a=pb[o];
#pragma unroll
    for (int cc=0;cc<32;cc++) a+=vv[cc]*pw[o*32+cc];
    size_t off=((size_t)b*32+o)*NP+n;
    out[off]=xsum[off]+a;
  }
}

extern "C" void kernel_launch(void* const* d_in, const int* in_sizes, int n_in,
                              void* d_out, int out_size, void* d_ws, size_t ws_size,
                              hipStream_t stream) {
  (void)in_sizes; (void)n_in; (void)out_size; (void)ws_size;
  const float* x       =(const float*)d_in[0];
  const float* cab_w1  =(const float*)d_in[1];
  const float* cab_w2  =(const float*)d_in[2];
  const float* cab_aw1 =(const float*)d_in[3];
  const float* cab_aw2 =(const float*)d_in[4];
  const float* sq1_w   =(const float*)d_in[5];
  const float* sq2_w   =(const float*)d_in[6];
  const float* ca_qkv_w=(const float*)d_in[7];
  const float* ca_fus_w=(const float*)d_in[8];
  const float* sa_qkv_w=(const float*)d_in[9];
  const float* sa_fus_w=(const float*)d_in[10];
  const float* un1_w   =(const float*)d_in[11];
  const float* un2_w   =(const float*)d_in[12];
  const float* da_w1   =(const float*)d_in[13];
  const float* da_dw_w =(const float*)d_in[14];
  const float* da_pw   =(const float*)d_in[15];
  const float* cab_b1  =(const float*)d_in[16];
  const float* cab_b2  =(const float*)d_in[17];
  const float* cab_ab1 =(const float*)d_in[18];
  const float* cab_ab2 =(const float*)d_in[19];
  const float* sq1_b   =(const float*)d_in[20];
  const float* sq2_b   =(const float*)d_in[21];
  const float* ca_qkv_b=(const float*)d_in[22];
  const float* ca_fus_b=(const float*)d_in[23];
  const float* sa_qkv_b=(const float*)d_in[24];
  const float* sa_fus_b=(const float*)d_in[25];
  const float* un1_b   =(const float*)d_in[26];
  const float* un2_b   =(const float*)d_in[27];
  const float* da_b1   =(const float*)d_in[28];
  const float* da_dw_b =(const float*)d_in[29];
  const float* da_pb   =(const float*)d_in[30];
  const float* ln1_w   =(const float*)d_in[31];
  const float* ln1_b   =(const float*)d_in[32];
  const float* ln2_w   =(const float*)d_in[33];
  const float* ln2_b   =(const float*)d_in[34];
  const float* ca_t    =(const float*)d_in[35];
  const float* sa_t    =(const float*)d_in[36];

  float* ws=(float*)d_ws;
  float* xn    = ws;               // 589824 (dead after phB; reused as d1)
  float* z1    = ws + 589824;      // 147456
  float* c1b   = ws + 737280;      // 147456
  float* cb    = ws + 884736;      // 589824 (cbuf; reused as dg after k_un2)
  float* u     = ws + 1474560;     // 73728
  float* psb   = ws + 1548288;     // 147456
  float* xsm   = ws + 1695744;     // 589824
  float* ypart = ws + 2285568;     // 2304
  float* spart = ws + 2287872;     // 720 (+pad)
  float2* qarr = (float2*)(ws + 2288640);  // 32*2304*2 = 147456 floats
  float* mompart = ws + 2436096;   // 288*78 = 22464
  float* d1    = xn;               // alias: xn dead after phB
  float* dg    = cb;               // alias: cbuf dead after k_un2

  k_ln1 <<<576, 256,0,stream>>>(x, ln1_w, ln1_b, sq1_w, sq1_b, xn, z1);
  k_phB <<<720, 256,0,stream>>>(xn, cab_w1, cab_b1, z1, sq2_w, sq2_b, c1b, u, spart);
  k_phC <<<864, 256,0,stream>>>(c1b, cab_w2, cab_b2, cb, ypart,
                                u, spart, ca_qkv_w, ca_qkv_b, ca_t, ca_fus_w, ca_fus_b,
                                sa_qkv_w, sa_qkv_b, qarr, mompart);
  k_rows<<<144, 256,0,stream>>>(qarr, mompart, sa_t, sa_qkv_w, sa_qkv_b,
                                sa_fus_w, sa_fus_b, un1_w, un1_b, psb);
  k_un2 <<<576, 256,0,stream>>>(psb, ypart, cab_aw1, cab_ab1, cab_aw2, cab_ab2,
                                un2_w, un2_b, x, cb, ln2_w, ln2_b, da_w1, da_b1, xsm, d1);
  k_dw  <<<1152,256,0,stream>>>(d1, da_dw_w, da_dw_b, dg);
  k_fin <<<576, 256,0,stream>>>(dg, da_pw, da_pb, xsm, (float*)d_out);
}